// Round 14
// baseline (662.765 us; speedup 1.0000x reference)
//
#include <hip/hip_runtime.h>

typedef __attribute__((ext_vector_type(8))) short short8;
typedef __attribute__((ext_vector_type(4))) float floatx4;
typedef __attribute__((ext_vector_type(2))) float floatx2;
typedef __attribute__((ext_vector_type(4))) unsigned short ushort4v;

#define DEVI static __device__ __forceinline__

DEVI unsigned short f2bf(float f) {
  unsigned int u = __float_as_uint(f);
  u = (u + 0x7fffu + ((u >> 16) & 1u)) >> 16;   // RNE
  return (unsigned short)u;
}
DEVI float bf2f(unsigned short h) { return __uint_as_float(((unsigned int)h) << 16); }

// x staging LDS: [c][t] bf16, t in [0,128), swizzled
DEVI int ridx2(int c, int t) { return c * 128 + (t ^ ((c & 7) << 3)); }
// frag-order LDS: row in [0,128), 32 chunks of 8 bf16, chunk-swizzled
DEVI int xnaddr(int row, int chunk) { return row * 256 + (((chunk) ^ (row & 7)) << 3); }

// packed weight fragment: rb = 16-row tile (0..47 Wqkv, 48..63 Wout), kc = K/32.
DEVI short8 wpfrag(const unsigned short* __restrict__ wbf, int rb, int kc, int lane) {
  return *(const short8*)&wbf[(((size_t)rb * 8 + kc) * 64 + lane) * 8];
}

// ---------------- weight fp32 -> packed bf16 fragments ----------------
__global__ void wconv(const float* __restrict__ wqkv, const float* __restrict__ wout,
                      unsigned short* __restrict__ wbf) {
  int cl = blockIdx.x * 256 + threadIdx.x;   // 0..32767 (grid 128)
  int lane = cl & 63;
  int rbkc = cl >> 6;
  int kc = rbkc & 7;
  int rb = rbkc >> 3;                        // 0..63
  int g = lane >> 4, l15 = lane & 15;
  const float* src = (rb < 48) ? wqkv : wout;
  int row = (rb < 48) ? rb * 16 + l15 : (rb - 48) * 16 + l15;
#pragma unroll
  for (int h = 0; h < 2; ++h)
#pragma unroll
    for (int e = 0; e < 4; ++e)
      wbf[(size_t)cl * 8 + h * 4 + e] = f2bf(src[row * 256 + kc * 32 + h * 16 + g * 4 + e]);
}

// ================= k0: LN -> xn (global, MFMA-fragment-lane order) =========
// xng chunk ci = win*32 + nt*8 + kc per strip; chunk = 64 lanes x 16B where
// lane l holds xn[token srow_win(nt*16+(l&15))][ch kc*32 + (l>>4)*4 + {0..3,16..19}]
__global__ __launch_bounds__(512, 2) void k0_ln(
    const float* __restrict__ x, const float* __restrict__ gamma,
    const float* __restrict__ beta, unsigned short* __restrict__ xng) {
  __shared__ __align__(16) unsigned short sx[128 * 256];   // 64KB: x -> xn frags
  __shared__ floatx2 psum[4][128];                          // 4KB LN partials

  const int tid = threadIdx.x;
  const int lane = tid & 63;
  const int g = lane >> 4;
  const int l15 = lane & 15;

  const int id = ((blockIdx.x & 7) << 8) + (blockIdx.x >> 3);
  const int b = id >> 9;
  const int wy = (id >> 4) & 31;
  const int wxp = id & 15;
  const size_t xbase = ((size_t)b << 24) + (size_t)(wy * 8) * 256 + (size_t)(wxp * 16);

  // ---- Phase A: load x strip -> sx bf16 [c][t] ----
#pragma unroll
  for (int it = 0; it < 16; ++it) {
    int s = it * 512 + tid;
    int c = s >> 5, i = (s >> 2) & 7, j4 = s & 3;
    floatx4 v = *(const floatx4*)(x + xbase + (size_t)c * 65536 + i * 256 + j4 * 4);
    ushort4v u;
    u.x = f2bf(v.x); u.y = f2bf(v.y); u.z = f2bf(v.z); u.w = f2bf(v.w);
    *(ushort4v*)&sx[ridx2(c, i * 16 + j4 * 4)] = u;
  }
  __syncthreads();

  // ---- Phase B1: LN partials; 64 channels kept in regs ----
  const int t = tid & 127;
  const int q = tid >> 7;
  unsigned int xr[32];
  float s1 = 0.f, s2 = 0.f;
#pragma unroll
  for (int cc = 0; cc < 32; ++cc) {
    unsigned int u0 = sx[ridx2(q * 64 + 2 * cc, t)];
    unsigned int u1 = sx[ridx2(q * 64 + 2 * cc + 1, t)];
    xr[cc] = u0 | (u1 << 16);
    float a = __uint_as_float(u0 << 16);
    float c2 = __uint_as_float(u1 << 16);
    s1 += a + c2;
    s2 = fmaf(a, a, s2); s2 = fmaf(c2, c2, s2);
  }
  { floatx2 p; p.x = s1; p.y = s2; psum[q][t] = p; }
  __syncthreads();

  float S1 = 0.f, S2 = 0.f;
#pragma unroll
  for (int p = 0; p < 4; ++p) { floatx2 pp = psum[p][t]; S1 += pp.x; S2 += pp.y; }
  const float mu = S1 * (1.f / 256.f);
  const float rstd = rsqrtf(S2 * (1.f / 256.f) - mu * mu + 1e-5f);

  // ---- Phase B2: write xn bf16 in fragment order (over sx) ----
#pragma unroll
  for (int kk = 0; kk < 2; ++kk) {
    int kc = q * 2 + kk;
#pragma unroll
    for (int gc = 0; gc < 4; ++gc) {
      short8 s8;
#pragma unroll
      for (int hf = 0; hf < 2; ++hf)
#pragma unroll
        for (int e = 0; e < 4; ++e) {
          int lc = kk * 32 + hf * 16 + gc * 4 + e;
          int c = q * 64 + lc;
          unsigned int u = xr[lc >> 1];
          float xv = __uint_as_float((lc & 1) ? (u & 0xffff0000u) : (u << 16));
          float val = (xv - mu) * rstd * gamma[c] + beta[c];
          s8[hf * 4 + e] = (short)f2bf(val);
        }
      *(short8*)&sx[xnaddr(t, kc * 4 + gc)] = s8;
    }
  }
  __syncthreads();

  // ---- copy-out: gather per-chunk fragment-lane order, coalesced 16B/lane ----
  const int wv = tid >> 6;
#pragma unroll
  for (int it = 0; it < 8; ++it) {
    int ci = it * 8 + wv;                 // 0..63
    int win = ci >> 5, nt = (ci >> 3) & 3, kc = ci & 7;
    int tq = nt * 16 + l15;
    int tl = ((tq >> 3) << 4) + win * 8 + (tq & 7);
    short8 v = *(const short8*)&sx[xnaddr(tl, kc * 4 + g)];
    *(short8*)&xng[(((size_t)id * 64 + ci) * 64 + lane) * 8] = v;
  }
}

// ================= k1: QKV GEMMs + window attention (no LDS) ==============
// 256 threads, wave = head, win-loop x2. Token frags stream from xng
// (coalesced 1KB chunks); weights packed in wbf. Q+K fused over shared tf.
__global__ __launch_bounds__(256, 1) void k1_qkv_attn(
    const unsigned short* __restrict__ xng, const unsigned short* __restrict__ wbf,
    unsigned short* __restrict__ o_scr) {
  const int tid = threadIdx.x;
  const int lane = tid & 63;
  const int head = tid >> 6;
  const int g = lane >> 4;
  const int l15 = lane & 15;

  const int id = ((blockIdx.x & 7) << 8) + (blockIdx.x >> 3);
  const int b = id >> 9;
  const int wy = (id >> 4) & 31;
  const int wxp = id & 15;

  const float CEXP = 0.125f * 1.44269504088896f;

  auto tfrag = [&](int win, int nt, int kc) -> short8 {
    return *(const short8*)&xng[(((size_t)id * 64 + win * 32 + nt * 8 + kc) * 64 + lane) * 8];
  };

#pragma unroll 1
  for (int win = 0; win < 2; ++win) {
    // ---- Q+K GEMMs fused (shared token frags) ----
    floatx4 accQ[4][4] = {}, accK[4][4] = {};
#pragma unroll
    for (int kc = 0; kc < 8; ++kc) {
      short8 tf[4], wq[4], wk[4];
#pragma unroll
      for (int nt = 0; nt < 4; ++nt) tf[nt] = tfrag(win, nt, kc);
#pragma unroll
      for (int mt = 0; mt < 4; ++mt) {
        wq[mt] = wpfrag(wbf, head * 4 + mt, kc, lane);
        wk[mt] = wpfrag(wbf, 16 + head * 4 + mt, kc, lane);
      }
#pragma unroll
      for (int mt = 0; mt < 4; ++mt)
#pragma unroll
        for (int nt = 0; nt < 4; ++nt) {
          accQ[mt][nt] = __builtin_amdgcn_mfma_f32_16x16x32_bf16(wq[mt], tf[nt], accQ[mt][nt], 0, 0, 0);
          accK[mt][nt] = __builtin_amdgcn_mfma_f32_16x16x32_bf16(wk[mt], tf[nt], accK[mt][nt], 0, 0, 0);
        }
    }
    short8 qf[4][2], kf[4][2];
#pragma unroll
    for (int nt = 0; nt < 4; ++nt)
#pragma unroll
      for (int ks = 0; ks < 2; ++ks) {
        short8 fq, fk;
#pragma unroll
        for (int e = 0; e < 4; ++e) {
          fq[e]     = (short)f2bf(accQ[2 * ks][nt][e]);
          fq[4 + e] = (short)f2bf(accQ[2 * ks + 1][nt][e]);
          fk[e]     = (short)f2bf(accK[2 * ks][nt][e]);
          fk[4 + e] = (short)f2bf(accK[2 * ks + 1][nt][e]);
        }
        qf[nt][ks] = fq;
        kf[nt][ks] = fk;
      }

    // ---- streamed S^T + softmax per q-tile ----
    short8 pf[4][2];
#pragma unroll
    for (int nts = 0; nts < 4; ++nts) {
      floatx4 sac[4] = {};
#pragma unroll
      for (int ks = 0; ks < 2; ++ks)
#pragma unroll
        for (int mts = 0; mts < 4; ++mts)
          sac[mts] = __builtin_amdgcn_mfma_f32_16x16x32_bf16(kf[mts][ks], qf[nts][ks], sac[mts], 0, 0, 0);

      float m = sac[0][0];
#pragma unroll
      for (int mts = 0; mts < 4; ++mts)
#pragma unroll
        for (int r = 0; r < 4; ++r) m = fmaxf(m, sac[mts][r]);
      m = fmaxf(m, __shfl_xor(m, 16));
      m = fmaxf(m, __shfl_xor(m, 32));
      float sum = 0.f;
#pragma unroll
      for (int mts = 0; mts < 4; ++mts)
#pragma unroll
        for (int r = 0; r < 4; ++r) {
          float p = __builtin_amdgcn_exp2f((sac[mts][r] - m) * CEXP);
          sac[mts][r] = p;
          sum += p;
        }
      sum += __shfl_xor(sum, 16);
      sum += __shfl_xor(sum, 32);
      float inv = __builtin_amdgcn_rcpf(sum);
#pragma unroll
      for (int ks = 0; ks < 2; ++ks) {
        short8 f;
#pragma unroll
        for (int e = 0; e < 4; ++e) {
          f[e]     = (short)f2bf(sac[2 * ks][e] * inv);
          f[4 + e] = (short)f2bf(sac[2 * ks + 1][e] * inv);
        }
        pf[nts][ks] = f;
      }
    }

    // ---- V GEMM (re-read token frags; qf/kf dead) ----
    short8 vf[4][2];
    {
      floatx4 acc[4][4] = {};
#pragma unroll
      for (int kc = 0; kc < 8; ++kc) {
        short8 tf[4], wv4[4];
#pragma unroll
        for (int mt = 0; mt < 4; ++mt) tf[mt] = tfrag(win, mt, kc);
#pragma unroll
        for (int nt = 0; nt < 4; ++nt) wv4[nt] = wpfrag(wbf, 32 + head * 4 + nt, kc, lane);
#pragma unroll
        for (int mt = 0; mt < 4; ++mt)
#pragma unroll
          for (int nt = 0; nt < 4; ++nt)
            acc[mt][nt] = __builtin_amdgcn_mfma_f32_16x16x32_bf16(tf[mt], wv4[nt], acc[mt][nt], 0, 0, 0);
      }
#pragma unroll
      for (int nt = 0; nt < 4; ++nt)
#pragma unroll
        for (int ks = 0; ks < 2; ++ks) {
          short8 f;
#pragma unroll
          for (int e = 0; e < 4; ++e) {
            f[e]     = (short)f2bf(acc[2 * ks][nt][e]);
            f[4 + e] = (short)f2bf(acc[2 * ks + 1][nt][e]);
          }
          vf[nt][ks] = f;
        }
    }

    // ---- O^T = mfma(vf, pf); direct coalesced o_scr store ----
    floatx4 oa2[4][4];
#pragma unroll
    for (int dt = 0; dt < 4; ++dt)
#pragma unroll
      for (int ntq = 0; ntq < 4; ++ntq) oa2[dt][ntq] = floatx4{0.f, 0.f, 0.f, 0.f};
#pragma unroll
    for (int ks = 0; ks < 2; ++ks)
#pragma unroll
      for (int dt = 0; dt < 4; ++dt)
#pragma unroll
        for (int ntq = 0; ntq < 4; ++ntq)
          oa2[dt][ntq] = __builtin_amdgcn_mfma_f32_16x16x32_bf16(vf[dt][ks], pf[ntq][ks], oa2[dt][ntq], 0, 0, 0);

#pragma unroll
    for (int dtp = 0; dtp < 2; ++dtp)
#pragma unroll
      for (int ntq = 0; ntq < 4; ++ntq) {
        int tq = ntq * 16 + l15;
        size_t orow = ((size_t)b * 256 + wy * 8 + (tq >> 3)) * 256 + wxp * 16 + win * 8 + (tq & 7);
        short8 o8;
#pragma unroll
        for (int r = 0; r < 4; ++r) {
          o8[r]     = (short)f2bf(oa2[2 * dtp][ntq][r]);
          o8[4 + r] = (short)f2bf(oa2[2 * dtp + 1][ntq][r]);
        }
        *(short8*)&o_scr[orow * 256 + head * 64 + dtp * 32 + g * 8] = o8;
      }
  }
}

// ================= k2: out-proj + residual, NCHW float4 epilogue ==========
__global__ __launch_bounds__(512, 2) void k2_proj(
    const unsigned short* __restrict__ o_scr, const float* __restrict__ x,
    const unsigned short* __restrict__ wbf, float* __restrict__ out) {
  __shared__ __align__(16) unsigned short sx[128 * 256];   // 64KB o-frag staging

  const int tid = threadIdx.x;
  const int lane = tid & 63;
  const int wv = tid >> 6;
  const int g = lane >> 4;
  const int l15 = lane & 15;

  const int b = blockIdx.x >> 8;
  const int h = blockIdx.x & 255;

  auto ldsfrag = [&](int row, int kc) -> short8 {
    return *(const short8*)&sx[xnaddr(row, kc * 4 + g)];
  };

#pragma unroll
  for (int hf = 0; hf < 2; ++hf) {
    const size_t obase = (((size_t)b * 256 + h) * 256 + hf * 128) * 256;
#pragma unroll
    for (int it = 0; it < 8; ++it) {
      int s = it * 512 + tid;
      int tl = s >> 5, cid = s & 31;
      short8 v = *(const short8*)&o_scr[obase + tl * 256 + cid * 8];
      *(short8*)&sx[tl * 256 + ((cid ^ (tl & 7)) << 3)] = v;
    }
    __syncthreads();

    floatx4 fa[8][2] = {};   // [nt = token tile][mt = co tile]
#pragma unroll
    for (int kc = 0; kc < 8; ++kc) {
      short8 Atok[8], Bw[2];
#pragma unroll
      for (int nt = 0; nt < 8; ++nt) Atok[nt] = ldsfrag(nt * 16 + l15, kc);
#pragma unroll
      for (int mt = 0; mt < 2; ++mt)
        Bw[mt] = wpfrag(wbf, 48 + wv * 2 + mt, kc, lane);
#pragma unroll
      for (int nt = 0; nt < 8; ++nt)
#pragma unroll
        for (int mt = 0; mt < 2; ++mt)
          fa[nt][mt] = __builtin_amdgcn_mfma_f32_16x16x32_bf16(Atok[nt], Bw[mt], fa[nt][mt], 0, 0, 0);
    }

#pragma unroll
    for (int nt = 0; nt < 8; ++nt)
#pragma unroll
      for (int mt = 0; mt < 2; ++mt) {
        int co = wv * 32 + mt * 16 + l15;
        size_t addr = (((size_t)(b * 256 + co)) << 16) + (size_t)h * 256 +
                      hf * 128 + nt * 16 + 4 * g;
        floatx4 xv = *(const floatx4*)(x + addr);
        floatx4 o;
#pragma unroll
        for (int r = 0; r < 4; ++r) o[r] = fa[nt][mt][r] + xv[r];
        *(floatx4*)(out + addr) = o;
      }
    __syncthreads();
  }
}

// ================= fallback (round-13 fused kernel) if d_ws too small ======
__global__ __launch_bounds__(512, 2) void fused_fallback(
    const float* __restrict__ x, const float* __restrict__ gamma,
    const float* __restrict__ beta, const unsigned short* __restrict__ wbf,
    float* __restrict__ out) {
  __shared__ __align__(16) unsigned short sres[256 * 128];
  __shared__ __align__(16) unsigned short sxn[128 * 256];

  const int tid = threadIdx.x;
  const int lane = tid & 63;
  const int wv = tid >> 6;
  const int g = lane >> 4;
  const int l15 = lane & 15;

  const int id = ((blockIdx.x & 7) << 8) + (blockIdx.x >> 3);
  const int b = id >> 9;
  const int wy = (id >> 4) & 31;
  const int wxp = id & 15;
  const size_t xbase = ((size_t)b << 24) + (size_t)(wy * 8) * 256 + (size_t)(wxp * 16);

#pragma unroll
  for (int it = 0; it < 16; ++it) {
    int s = it * 512 + tid;
    int c = s >> 5, i = (s >> 2) & 7, j4 = s & 3;
    floatx4 v = *(const floatx4*)(x + xbase + (size_t)c * 65536 + i * 256 + j4 * 4);
    ushort4v u;
    u.x = f2bf(v.x); u.y = f2bf(v.y); u.z = f2bf(v.z); u.w = f2bf(v.w);
    *(ushort4v*)&sres[ridx2(c, i * 16 + j4 * 4)] = u;
  }
  __syncthreads();

  const int t = tid & 127;
  const int q = tid >> 7;
  float s1 = 0.f, s2 = 0.f;
#pragma unroll 8
  for (int cc = 0; cc < 64; ++cc) {
    float xv = bf2f(sres[ridx2(q * 64 + cc, t)]);
    s1 += xv; s2 += xv * xv;
  }
  { floatx2 p; p.x = s1; p.y = s2; ((floatx2*)sxn)[q * 128 + t] = p; }
  __syncthreads();

  float S1 = 0.f, S2 = 0.f;
#pragma unroll
  for (int p = 0; p < 4; ++p) {
    floatx2 pp = ((const floatx2*)sxn)[p * 128 + t];
    S1 += pp.x; S2 += pp.y;
  }
  const float mu = S1 * (1.f / 256.f);
  const float rstd = rsqrtf(S2 * (1.f / 256.f) - mu * mu + 1e-5f);
  __syncthreads();

#pragma unroll
  for (int kk = 0; kk < 2; ++kk) {
    int kc = q * 2 + kk;
#pragma unroll
    for (int gc = 0; gc < 4; ++gc) {
      short8 s8;
#pragma unroll
      for (int hf = 0; hf < 2; ++hf)
#pragma unroll
        for (int e = 0; e < 4; ++e) {
          int c = kc * 32 + hf * 16 + gc * 4 + e;
          float xv = bf2f(sres[ridx2(c, t)]);
          float val = (xv - mu) * rstd * gamma[c] + beta[c];
          s8[hf * 4 + e] = (short)f2bf(val);
        }
      *(short8*)&sxn[xnaddr(t, kc * 4 + gc)] = s8;
    }
  }
  __syncthreads();

  auto ldsfrag = [&](int row, int kc) -> short8 {
    return *(const short8*)&sxn[xnaddr(row, kc * 4 + g)];
  };

  const int head = wv >> 1;
  const int win = wv & 1;
  auto srow = [&](int tl) { return (((tl) >> 3) << 4) + win * 8 + ((tl) & 7); };

  short8 qkf[2][4][2];
#pragma unroll
  for (int qk = 0; qk < 2; ++qk) {
    floatx4 acc[4][4] = {};
    const int rbq = qk * 16 + head * 4;
#pragma unroll
    for (int kc = 0; kc < 8; ++kc) {
      short8 Bv[4], Av[4];
#pragma unroll
      for (int nt = 0; nt < 4; ++nt) Bv[nt] = ldsfrag(srow(nt * 16 + l15), kc);
#pragma unroll
      for (int mt = 0; mt < 4; ++mt)
        Av[mt] = wpfrag(wbf, rbq + mt, kc, lane);
#pragma unroll
      for (int mt = 0; mt < 4; ++mt)
#pragma unroll
        for (int nt = 0; nt < 4; ++nt)
          acc[mt][nt] = __builtin_amdgcn_mfma_f32_16x16x32_bf16(Av[mt], Bv[nt], acc[mt][nt], 0, 0, 0);
    }
#pragma unroll
    for (int nt = 0; nt < 4; ++nt)
#pragma unroll
      for (int ks = 0; ks < 2; ++ks) {
        short8 f;
#pragma unroll
        for (int e = 0; e < 4; ++e) {
          f[e]     = (short)f2bf(acc[2 * ks][nt][e]);
          f[4 + e] = (short)f2bf(acc[2 * ks + 1][nt][e]);
        }
        qkf[qk][nt][ks] = f;
      }
  }

  floatx4 sa[4][4] = {};
#pragma unroll
  for (int ks = 0; ks < 2; ++ks)
#pragma unroll
    for (int mts = 0; mts < 4; ++mts)
#pragma unroll
      for (int nts = 0; nts < 4; ++nts)
        sa[mts][nts] = __builtin_amdgcn_mfma_f32_16x16x32_bf16(qkf[1][mts][ks], qkf[0][nts][ks], sa[mts][nts], 0, 0, 0);

  short8 pf[4][2];
  const float CEXP = 0.125f * 1.44269504088896f;
#pragma unroll
  for (int nts = 0; nts < 4; ++nts) {
    float m = sa[0][nts][0];
#pragma unroll
    for (int mts = 0; mts < 4; ++mts)
#pragma unroll
      for (int r = 0; r < 4; ++r) m = fmaxf(m, sa[mts][nts][r]);
    m = fmaxf(m, __shfl_xor(m, 16));
    m = fmaxf(m, __shfl_xor(m, 32));
    float sum = 0.f;
#pragma unroll
    for (int mts = 0; mts < 4; ++mts)
#pragma unroll
      for (int r = 0; r < 4; ++r) {
        float p = __builtin_amdgcn_exp2f((sa[mts][nts][r] - m) * CEXP);
        sa[mts][nts][r] = p;
        sum += p;
      }
    sum += __shfl_xor(sum, 16);
    sum += __shfl_xor(sum, 32);
    float inv = __builtin_amdgcn_rcpf(sum);
#pragma unroll
    for (int ks = 0; ks < 2; ++ks) {
      short8 f;
#pragma unroll
      for (int e = 0; e < 4; ++e) {
        f[e]     = (short)f2bf(sa[2 * ks][nts][e] * inv);
        f[4 + e] = (short)f2bf(sa[2 * ks + 1][nts][e] * inv);
      }
      pf[nts][ks] = f;
    }
  }

  short8 vf[4][2];
  {
    floatx4 acc[4][4] = {};
#pragma unroll
    for (int kc = 0; kc < 8; ++kc) {
      short8 Av[4], Bv[4];
#pragma unroll
      for (int mt = 0; mt < 4; ++mt) Av[mt] = ldsfrag(srow(mt * 16 + l15), kc);
#pragma unroll
      for (int nt = 0; nt < 4; ++nt)
        Bv[nt] = wpfrag(wbf, 32 + head * 4 + nt, kc, lane);
#pragma unroll
      for (int mt = 0; mt < 4; ++mt)
#pragma unroll
        for (int nt = 0; nt < 4; ++nt)
          acc[mt][nt] = __builtin_amdgcn_mfma_f32_16x16x32_bf16(Av[mt], Bv[nt], acc[mt][nt], 0, 0, 0);
    }
#pragma unroll
    for (int nt = 0; nt < 4; ++nt)
#pragma unroll
      for (int ks = 0; ks < 2; ++ks) {
        short8 f;
#pragma unroll
        for (int e = 0; e < 4; ++e) {
          f[e]     = (short)f2bf(acc[2 * ks][nt][e]);
          f[4 + e] = (short)f2bf(acc[2 * ks + 1][nt][e]);
        }
        vf[nt][ks] = f;
      }
  }

  floatx4 oa[4][4] = {};
#pragma unroll
  for (int ks = 0; ks < 2; ++ks)
#pragma unroll
    for (int ntq = 0; ntq < 4; ++ntq)
#pragma unroll
      for (int dt = 0; dt < 4; ++dt)
        oa[ntq][dt] = __builtin_amdgcn_mfma_f32_16x16x32_bf16(pf[ntq][ks], vf[dt][ks], oa[ntq][dt], 0, 0, 0);

  __syncthreads();

#pragma unroll
  for (int ntq = 0; ntq < 4; ++ntq)
#pragma unroll
    for (int dt = 0; dt < 4; ++dt) {
      int c = head * 64 + dt * 16 + l15;
      int kc = c >> 5, hf = (c >> 4) & 1, gc = (c >> 2) & 3, e = c & 3;
#pragma unroll
      for (int r = 0; r < 4; ++r) {
        int tq = ntq * 16 + 4 * g + r;
        int sr = srow(tq);
        sxn[sr * 256 + (((kc * 4 + gc) ^ (sr & 7)) << 3) + hf * 4 + e] =
            f2bf(oa[ntq][dt][r]);
      }
    }
  __syncthreads();

  floatx4 fa[2][8] = {};
#pragma unroll
  for (int kc = 0; kc < 8; ++kc) {
    short8 Bv[8], Av[2];
#pragma unroll
    for (int nt = 0; nt < 8; ++nt) Bv[nt] = ldsfrag(nt * 16 + l15, kc);
#pragma unroll
    for (int mt = 0; mt < 2; ++mt)
      Av[mt] = wpfrag(wbf, 48 + wv * 2 + mt, kc, lane);
#pragma unroll
    for (int mt = 0; mt < 2; ++mt)
#pragma unroll
      for (int nt = 0; nt < 8; ++nt)
        fa[mt][nt] = __builtin_amdgcn_mfma_f32_16x16x32_bf16(Av[mt], Bv[nt], fa[mt][nt], 0, 0, 0);
  }

#pragma unroll
  for (int mt = 0; mt < 2; ++mt)
#pragma unroll
    for (int nt = 0; nt < 8; ++nt)
#pragma unroll
      for (int r = 0; r < 4; ++r) {
        int co = wv * 32 + mt * 16 + 4 * g + r;
        int tt = nt * 16 + l15;
        float val = fa[mt][nt][r] + bf2f(sres[ridx2(co, tt)]);
        out[((size_t)(b * 256 + co) << 16) + (size_t)(wy * 8 + (tt >> 4)) * 256 +
            (wxp * 16 + (tt & 15))] = val;
      }
}

extern "C" void kernel_launch(void* const* d_in, const int* in_sizes, int n_in,
                              void* d_out, int out_size, void* d_ws, size_t ws_size,
                              hipStream_t stream) {
  const float* x     = (const float*)d_in[0];
  const float* gamma = (const float*)d_in[1];
  const float* beta  = (const float*)d_in[2];
  const float* wqkv  = (const float*)d_in[3];
  const float* wout  = (const float*)d_in[4];
  float* out = (float*)d_out;

  unsigned short* wbf   = (unsigned short*)d_ws;             // 512 KB packed bf16 weights
  unsigned short* o_scr = wbf + 262144;                      // 128 MB o scratch
  unsigned short* xng   = o_scr + 67108864;                  // 128 MB xn fragment chunks

  const size_t need = 512 * 1024 + (size_t)256 * 1024 * 1024;

  wconv<<<128, 256, 0, stream>>>(wqkv, wout, wbf);
  if (ws_size >= need) {
    k0_ln<<<2048, 512, 0, stream>>>(x, gamma, beta, xng);
    k1_qkv_attn<<<2048, 256, 0, stream>>>(xng, wbf, o_scr);
    k2_proj<<<1024, 512, 0, stream>>>(o_scr, x, wbf, out);
  } else {
    fused_fallback<<<2048, 512, 0, stream>>>(x, gamma, beta, wbf, out);
  }
}

// Round 15
// 555.055 us; speedup vs baseline: 1.1941x; 1.1941x over previous
//
#include <hip/hip_runtime.h>

typedef __attribute__((ext_vector_type(8))) short short8;
typedef __attribute__((ext_vector_type(4))) float floatx4;
typedef __attribute__((ext_vector_type(2))) float floatx2;
typedef __attribute__((ext_vector_type(4))) unsigned short ushort4v;

#define DEVI static __device__ __forceinline__

DEVI unsigned short f2bf(float f) {
  unsigned int u = __float_as_uint(f);
  u = (u + 0x7fffu + ((u >> 16) & 1u)) >> 16;   // RNE
  return (unsigned short)u;
}
DEVI float bf2f(unsigned short h) { return __uint_as_float(((unsigned int)h) << 16); }

// x staging LDS: [c][t] bf16, t in [0,128), swizzled (fallback only)
DEVI int ridx2(int c, int t) { return c * 128 + (t ^ ((c & 7) << 3)); }
// frag-order LDS: row in [0,128), 32 chunks of 8 bf16, chunk-swizzled
DEVI int xnaddr(int row, int chunk) { return row * 256 + (((chunk) ^ (row & 7)) << 3); }

// packed weight fragment: rb = 16-row tile (0..47 Wqkv, 48..63 Wout), kc = K/32.
DEVI short8 wpfrag(const unsigned short* __restrict__ wbf, int rb, int kc, int lane) {
  return *(const short8*)&wbf[(((size_t)rb * 8 + kc) * 64 + lane) * 8];
}

// ---------------- weight fp32 -> packed bf16 fragments ----------------
__global__ void wconv(const float* __restrict__ wqkv, const float* __restrict__ wout,
                      unsigned short* __restrict__ wbf) {
  int cl = blockIdx.x * 256 + threadIdx.x;   // 0..32767 (grid 128)
  int lane = cl & 63;
  int rbkc = cl >> 6;
  int kc = rbkc & 7;
  int rb = rbkc >> 3;                        // 0..63
  int g = lane >> 4, l15 = lane & 15;
  const float* src = (rb < 48) ? wqkv : wout;
  int row = (rb < 48) ? rb * 16 + l15 : (rb - 48) * 16 + l15;
#pragma unroll
  for (int h = 0; h < 2; ++h)
#pragma unroll
    for (int e = 0; e < 4; ++e)
      wbf[(size_t)cl * 8 + h * 4 + e] = f2bf(src[row * 256 + kc * 32 + h * 16 + g * 4 + e]);
}

// ================= k1a: LN + QKV GEMMs -> fragment scratch =================
// (512,2). r15: Phase A (x->LDS bf16 round trip) deleted — LN loads x straight
// from global into registers (64 indep 4B loads/thread, 4x64B segments/instr).
// LDS sx holds ONLY xn fragments. One fewer barrier on the critical chain.
__global__ __launch_bounds__(512, 2) void k1a_qkv(
    const float* __restrict__ x, const float* __restrict__ gamma,
    const float* __restrict__ beta, const unsigned short* __restrict__ wbf,
    unsigned short* __restrict__ frag) {
  __shared__ __align__(16) unsigned short sx[128 * 256];   // 64KB xn frags
  __shared__ floatx2 psum[4][128];                          // 4KB LN partials

  const int tid = threadIdx.x;
  const int lane = tid & 63;
  const int wv = tid >> 6;
  const int g = lane >> 4;
  const int l15 = lane & 15;

  // XCD-chunked swizzle (2048 blocks, 8 XCDs)
  const int id = ((blockIdx.x & 7) << 8) + (blockIdx.x >> 3);
  const int b = id >> 9;
  const int wy = (id >> 4) & 31;
  const int wxp = id & 15;
  const size_t xbase = ((size_t)b << 24) + (size_t)(wy * 8) * 256 + (size_t)(wxp * 16);

  // ---- Phase B1: LN partials; 64 channels loaded direct from global ----
  const int t = tid & 127;
  const int q = tid >> 7;          // wave-uniform
  const size_t tok_off = (size_t)((t >> 4) * 256 + (t & 15));
  unsigned int xr[32];
  float s1 = 0.f, s2 = 0.f;
#pragma unroll
  for (int cc = 0; cc < 32; ++cc) {
    float a0 = x[xbase + (size_t)(q * 64 + 2 * cc) * 65536 + tok_off];
    float a1 = x[xbase + (size_t)(q * 64 + 2 * cc + 1) * 65536 + tok_off];
    unsigned int u0 = f2bf(a0), u1 = f2bf(a1);
    xr[cc] = u0 | (u1 << 16);
    float a = __uint_as_float(u0 << 16);
    float c2 = __uint_as_float(u1 << 16);
    s1 += a + c2;
    s2 = fmaf(a, a, s2); s2 = fmaf(c2, c2, s2);
  }
  { floatx2 p; p.x = s1; p.y = s2; psum[q][t] = p; }
  __syncthreads();

  float S1 = 0.f, S2 = 0.f;
#pragma unroll
  for (int p = 0; p < 4; ++p) { floatx2 pp = psum[p][t]; S1 += pp.x; S2 += pp.y; }
  const float mu = S1 * (1.f / 256.f);
  const float rstd = rsqrtf(S2 * (1.f / 256.f) - mu * mu + 1e-5f);

  // ---- Phase B2: write xn bf16 in fragment order ----
#pragma unroll
  for (int kk = 0; kk < 2; ++kk) {
    int kc = q * 2 + kk;
#pragma unroll
    for (int gc = 0; gc < 4; ++gc) {
      short8 s8;
#pragma unroll
      for (int hf = 0; hf < 2; ++hf)
#pragma unroll
        for (int e = 0; e < 4; ++e) {
          int lc = kk * 32 + hf * 16 + gc * 4 + e;
          int c = q * 64 + lc;
          unsigned int u = xr[lc >> 1];
          float xv = __uint_as_float((lc & 1) ? (u & 0xffff0000u) : (u << 16));
          float val = (xv - mu) * rstd * gamma[c] + beta[c];
          s8[hf * 4 + e] = (short)f2bf(val);
        }
      *(short8*)&sx[xnaddr(t, kc * 4 + gc)] = s8;
    }
  }
  __syncthreads();

  auto ldsfrag = [&](int row, int kc) -> short8 {
    return *(const short8*)&sx[xnaddr(row, kc * 4 + g)];
  };

  const int head = wv >> 1;
  const int win = wv & 1;
  auto srow = [&](int tl) { return (((tl) >> 3) << 4) + win * 8 + ((tl) & 7); };

  // fragment scratch base for this (strip, head, win): 24 slots x 512 ushorts
  unsigned short* fr = frag + ((size_t)(id * 8 + wv) * 24) * 512 + (size_t)lane * 8;

  // ---- q^T, k^T GEMMs: stream fragments to scratch (slots 0..15) ----
#pragma unroll
  for (int qk = 0; qk < 2; ++qk) {
    floatx4 acc[4][4] = {};
    const int rbq = qk * 16 + head * 4;
#pragma unroll
    for (int kh = 0; kh < 2; ++kh) {
      short8 wreg[4][4];
#pragma unroll
      for (int kk = 0; kk < 4; ++kk)
#pragma unroll
        for (int mt = 0; mt < 4; ++mt)
          wreg[kk][mt] = wpfrag(wbf, rbq + mt, kh * 4 + kk, lane);
#pragma unroll
      for (int kk = 0; kk < 4; ++kk) {
        int kc = kh * 4 + kk;
        short8 Bv[4];
#pragma unroll
        for (int nt = 0; nt < 4; ++nt) Bv[nt] = ldsfrag(srow(nt * 16 + l15), kc);
#pragma unroll
        for (int mt = 0; mt < 4; ++mt)
#pragma unroll
          for (int nt = 0; nt < 4; ++nt)
            acc[mt][nt] = __builtin_amdgcn_mfma_f32_16x16x32_bf16(wreg[kk][mt], Bv[nt], acc[mt][nt], 0, 0, 0);
      }
    }
#pragma unroll
    for (int nt = 0; nt < 4; ++nt)
#pragma unroll
      for (int ks = 0; ks < 2; ++ks) {
        short8 f;
#pragma unroll
        for (int e = 0; e < 4; ++e) {
          f[e]     = (short)f2bf(acc[2 * ks][nt][e]);
          f[4 + e] = (short)f2bf(acc[2 * ks + 1][nt][e]);
        }
        *(short8*)&fr[(size_t)(qk * 8 + nt * 2 + ks) * 512] = f;
      }
  }

  // ---- v GEMM: stream fragments to scratch (slots 16..23) ----
  {
    floatx4 acc[4][4] = {};
#pragma unroll
    for (int kh = 0; kh < 2; ++kh) {
      short8 wreg[4][4];
#pragma unroll
      for (int kk = 0; kk < 4; ++kk)
#pragma unroll
        for (int nt = 0; nt < 4; ++nt)
          wreg[kk][nt] = wpfrag(wbf, 32 + head * 4 + nt, kh * 4 + kk, lane);
#pragma unroll
      for (int kk = 0; kk < 4; ++kk) {
        int kc = kh * 4 + kk;
        short8 Av[4];
#pragma unroll
        for (int mt = 0; mt < 4; ++mt) Av[mt] = ldsfrag(srow(mt * 16 + l15), kc);
#pragma unroll
        for (int mt = 0; mt < 4; ++mt)
#pragma unroll
          for (int nt = 0; nt < 4; ++nt)
            acc[mt][nt] = __builtin_amdgcn_mfma_f32_16x16x32_bf16(Av[mt], wreg[kk][nt], acc[mt][nt], 0, 0, 0);
      }
    }
#pragma unroll
    for (int nt = 0; nt < 4; ++nt)
#pragma unroll
      for (int ks = 0; ks < 2; ++ks) {
        short8 f;
#pragma unroll
        for (int e = 0; e < 4; ++e) {
          f[e]     = (short)f2bf(acc[2 * ks][nt][e]);
          f[4 + e] = (short)f2bf(acc[2 * ks + 1][nt][e]);
        }
        *(short8*)&fr[(size_t)(16 + nt * 2 + ks) * 512] = f;
      }
  }
}

// ================= k1b: pure-register window attention =====================
__global__ __launch_bounds__(256, 1) void k1b_attn(
    const unsigned short* __restrict__ frag, unsigned short* __restrict__ o_scr) {
  const int tid = threadIdx.x;
  const int lane = tid & 63;
  const int head = tid >> 6;       // 0..3
  const int g = lane >> 4;
  const int l15 = lane & 15;

  const int id = ((blockIdx.x & 7) << 8) + (blockIdx.x >> 3);
  const int b = id >> 9;
  const int wy = (id >> 4) & 31;
  const int wxp = id & 15;

  const float CEXP = 0.125f * 1.44269504088896f;

#pragma unroll 1
  for (int win = 0; win < 2; ++win) {
    const unsigned short* fr =
        frag + ((size_t)(id * 8 + head * 2 + win) * 24) * 512 + (size_t)lane * 8;

    short8 qkf[2][4][2];
#pragma unroll
    for (int qk = 0; qk < 2; ++qk)
#pragma unroll
      for (int nt = 0; nt < 4; ++nt)
#pragma unroll
        for (int ks = 0; ks < 2; ++ks)
          qkf[qk][nt][ks] = *(const short8*)&fr[(size_t)(qk * 8 + nt * 2 + ks) * 512];

    // ---- streamed S^T + softmax per q-tile ----
    short8 pf[4][2];
#pragma unroll
    for (int nts = 0; nts < 4; ++nts) {
      floatx4 sac[4] = {};
#pragma unroll
      for (int ks = 0; ks < 2; ++ks)
#pragma unroll
        for (int mts = 0; mts < 4; ++mts)
          sac[mts] = __builtin_amdgcn_mfma_f32_16x16x32_bf16(qkf[1][mts][ks], qkf[0][nts][ks], sac[mts], 0, 0, 0);

      float m = sac[0][0];
#pragma unroll
      for (int mts = 0; mts < 4; ++mts)
#pragma unroll
        for (int r = 0; r < 4; ++r) m = fmaxf(m, sac[mts][r]);
      m = fmaxf(m, __shfl_xor(m, 16));
      m = fmaxf(m, __shfl_xor(m, 32));
      float sum = 0.f;
#pragma unroll
      for (int mts = 0; mts < 4; ++mts)
#pragma unroll
        for (int r = 0; r < 4; ++r) {
          float p = __builtin_amdgcn_exp2f((sac[mts][r] - m) * CEXP);
          sac[mts][r] = p;
          sum += p;
        }
      sum += __shfl_xor(sum, 16);
      sum += __shfl_xor(sum, 32);
      float inv = __builtin_amdgcn_rcpf(sum);
#pragma unroll
      for (int ks = 0; ks < 2; ++ks) {
        short8 f;
#pragma unroll
        for (int e = 0; e < 4; ++e) {
          f[e]     = (short)f2bf(sac[2 * ks][e] * inv);
          f[4 + e] = (short)f2bf(sac[2 * ks + 1][e] * inv);
        }
        pf[nts][ks] = f;
      }
    }

    // ---- v fragments ----
    short8 vf[4][2];
#pragma unroll
    for (int nt = 0; nt < 4; ++nt)
#pragma unroll
      for (int ks = 0; ks < 2; ++ks)
        vf[nt][ks] = *(const short8*)&fr[(size_t)(16 + nt * 2 + ks) * 512];

    // ---- O^T = mfma(vf, pf); direct coalesced o_scr store ----
    floatx4 oa2[4][4];   // [dt][ntq]
#pragma unroll
    for (int dt = 0; dt < 4; ++dt)
#pragma unroll
      for (int ntq = 0; ntq < 4; ++ntq) oa2[dt][ntq] = floatx4{0.f, 0.f, 0.f, 0.f};
#pragma unroll
    for (int ks = 0; ks < 2; ++ks)
#pragma unroll
      for (int dt = 0; dt < 4; ++dt)
#pragma unroll
        for (int ntq = 0; ntq < 4; ++ntq)
          oa2[dt][ntq] = __builtin_amdgcn_mfma_f32_16x16x32_bf16(vf[dt][ks], pf[ntq][ks], oa2[dt][ntq], 0, 0, 0);

#pragma unroll
    for (int dtp = 0; dtp < 2; ++dtp)
#pragma unroll
      for (int ntq = 0; ntq < 4; ++ntq) {
        int tq = ntq * 16 + l15;
        size_t orow = ((size_t)b * 256 + wy * 8 + (tq >> 3)) * 256 + wxp * 16 + win * 8 + (tq & 7);
        short8 o8;
#pragma unroll
        for (int r = 0; r < 4; ++r) {
          o8[r]     = (short)f2bf(oa2[2 * dtp][ntq][r]);
          o8[4 + r] = (short)f2bf(oa2[2 * dtp + 1][ntq][r]);
        }
        *(short8*)&o_scr[orow * 256 + head * 64 + dtp * 32 + g * 8] = o8;
      }
  }
}

// ================= k2: out-proj + residual, NCHW float4 epilogue ==========
__global__ __launch_bounds__(512, 2) void k2_proj(
    const unsigned short* __restrict__ o_scr, const float* __restrict__ x,
    const unsigned short* __restrict__ wbf, float* __restrict__ out) {
  __shared__ __align__(16) unsigned short sx[128 * 256];   // 64KB o-frag staging

  const int tid = threadIdx.x;
  const int lane = tid & 63;
  const int wv = tid >> 6;
  const int g = lane >> 4;
  const int l15 = lane & 15;

  const int b = blockIdx.x >> 8;
  const int h = blockIdx.x & 255;

  auto ldsfrag = [&](int row, int kc) -> short8 {
    return *(const short8*)&sx[xnaddr(row, kc * 4 + g)];
  };

#pragma unroll
  for (int hf = 0; hf < 2; ++hf) {
    const size_t obase = (((size_t)b * 256 + h) * 256 + hf * 128) * 256;
#pragma unroll
    for (int it = 0; it < 8; ++it) {
      int s = it * 512 + tid;
      int tl = s >> 5, cid = s & 31;
      short8 v = *(const short8*)&o_scr[obase + tl * 256 + cid * 8];
      *(short8*)&sx[tl * 256 + ((cid ^ (tl & 7)) << 3)] = v;
    }
    __syncthreads();

    floatx4 fa[8][2] = {};   // [nt = token tile][mt = co tile]
#pragma unroll
    for (int kc = 0; kc < 8; ++kc) {
      short8 Atok[8], Bw[2];
#pragma unroll
      for (int nt = 0; nt < 8; ++nt) Atok[nt] = ldsfrag(nt * 16 + l15, kc);
#pragma unroll
      for (int mt = 0; mt < 2; ++mt)
        Bw[mt] = wpfrag(wbf, 48 + wv * 2 + mt, kc, lane);
#pragma unroll
      for (int nt = 0; nt < 8; ++nt)
#pragma unroll
        for (int mt = 0; mt < 2; ++mt)
          fa[nt][mt] = __builtin_amdgcn_mfma_f32_16x16x32_bf16(Atok[nt], Bw[mt], fa[nt][mt], 0, 0, 0);
    }

    // epilogue: lane holds 4 consecutive w (row = 4g+r) for one co (col = l15)
#pragma unroll
    for (int nt = 0; nt < 8; ++nt)
#pragma unroll
      for (int mt = 0; mt < 2; ++mt) {
        int co = wv * 32 + mt * 16 + l15;
        size_t addr = (((size_t)(b * 256 + co)) << 16) + (size_t)h * 256 +
                      hf * 128 + nt * 16 + 4 * g;
        floatx4 xv = *(const floatx4*)(x + addr);
        floatx4 o;
#pragma unroll
        for (int r = 0; r < 4; ++r) o[r] = fa[nt][mt][r] + xv[r];
        *(floatx4*)(out + addr) = o;
      }
    __syncthreads();
  }
}

// ================= fallback (round-13 fused kernel) if d_ws too small ======
__global__ __launch_bounds__(512, 2) void fused_fallback(
    const float* __restrict__ x, const float* __restrict__ gamma,
    const float* __restrict__ beta, const unsigned short* __restrict__ wbf,
    float* __restrict__ out) {
  __shared__ __align__(16) unsigned short sres[256 * 128];
  __shared__ __align__(16) unsigned short sxn[128 * 256];

  const int tid = threadIdx.x;
  const int lane = tid & 63;
  const int wv = tid >> 6;
  const int g = lane >> 4;
  const int l15 = lane & 15;

  const int id = ((blockIdx.x & 7) << 8) + (blockIdx.x >> 3);
  const int b = id >> 9;
  const int wy = (id >> 4) & 31;
  const int wxp = id & 15;
  const size_t xbase = ((size_t)b << 24) + (size_t)(wy * 8) * 256 + (size_t)(wxp * 16);

#pragma unroll
  for (int it = 0; it < 16; ++it) {
    int s = it * 512 + tid;
    int c = s >> 5, i = (s >> 2) & 7, j4 = s & 3;
    floatx4 v = *(const floatx4*)(x + xbase + (size_t)c * 65536 + i * 256 + j4 * 4);
    ushort4v u;
    u.x = f2bf(v.x); u.y = f2bf(v.y); u.z = f2bf(v.z); u.w = f2bf(v.w);
    *(ushort4v*)&sres[ridx2(c, i * 16 + j4 * 4)] = u;
  }
  __syncthreads();

  const int t = tid & 127;
  const int q = tid >> 7;
  float s1 = 0.f, s2 = 0.f;
#pragma unroll 8
  for (int cc = 0; cc < 64; ++cc) {
    float xv = bf2f(sres[ridx2(q * 64 + cc, t)]);
    s1 += xv; s2 += xv * xv;
  }
  { floatx2 p; p.x = s1; p.y = s2; ((floatx2*)sxn)[q * 128 + t] = p; }
  __syncthreads();

  float S1 = 0.f, S2 = 0.f;
#pragma unroll
  for (int p = 0; p < 4; ++p) {
    floatx2 pp = ((const floatx2*)sxn)[p * 128 + t];
    S1 += pp.x; S2 += pp.y;
  }
  const float mu = S1 * (1.f / 256.f);
  const float rstd = rsqrtf(S2 * (1.f / 256.f) - mu * mu + 1e-5f);
  __syncthreads();

#pragma unroll
  for (int kk = 0; kk < 2; ++kk) {
    int kc = q * 2 + kk;
#pragma unroll
    for (int gc = 0; gc < 4; ++gc) {
      short8 s8;
#pragma unroll
      for (int hf = 0; hf < 2; ++hf)
#pragma unroll
        for (int e = 0; e < 4; ++e) {
          int c = kc * 32 + hf * 16 + gc * 4 + e;
          float xv = bf2f(sres[ridx2(c, t)]);
          float val = (xv - mu) * rstd * gamma[c] + beta[c];
          s8[hf * 4 + e] = (short)f2bf(val);
        }
      *(short8*)&sxn[xnaddr(t, kc * 4 + gc)] = s8;
    }
  }
  __syncthreads();

  auto ldsfrag = [&](int row, int kc) -> short8 {
    return *(const short8*)&sxn[xnaddr(row, kc * 4 + g)];
  };

  const int head = wv >> 1;
  const int win = wv & 1;
  auto srow = [&](int tl) { return (((tl) >> 3) << 4) + win * 8 + ((tl) & 7); };

  short8 qkf[2][4][2];
#pragma unroll
  for (int qk = 0; qk < 2; ++qk) {
    floatx4 acc[4][4] = {};
    const int rbq = qk * 16 + head * 4;
#pragma unroll
    for (int kc = 0; kc < 8; ++kc) {
      short8 Bv[4], Av[4];
#pragma unroll
      for (int nt = 0; nt < 4; ++nt) Bv[nt] = ldsfrag(srow(nt * 16 + l15), kc);
#pragma unroll
      for (int mt = 0; mt < 4; ++mt)
        Av[mt] = wpfrag(wbf, rbq + mt, kc, lane);
#pragma unroll
      for (int mt = 0; mt < 4; ++mt)
#pragma unroll
        for (int nt = 0; nt < 4; ++nt)
          acc[mt][nt] = __builtin_amdgcn_mfma_f32_16x16x32_bf16(Av[mt], Bv[nt], acc[mt][nt], 0, 0, 0);
    }
#pragma unroll
    for (int nt = 0; nt < 4; ++nt)
#pragma unroll
      for (int ks = 0; ks < 2; ++ks) {
        short8 f;
#pragma unroll
        for (int e = 0; e < 4; ++e) {
          f[e]     = (short)f2bf(acc[2 * ks][nt][e]);
          f[4 + e] = (short)f2bf(acc[2 * ks + 1][nt][e]);
        }
        qkf[qk][nt][ks] = f;
      }
  }

  floatx4 sa[4][4] = {};
#pragma unroll
  for (int ks = 0; ks < 2; ++ks)
#pragma unroll
    for (int mts = 0; mts < 4; ++mts)
#pragma unroll
      for (int nts = 0; nts < 4; ++nts)
        sa[mts][nts] = __builtin_amdgcn_mfma_f32_16x16x32_bf16(qkf[1][mts][ks], qkf[0][nts][ks], sa[mts][nts], 0, 0, 0);

  short8 pf[4][2];
  const float CEXP = 0.125f * 1.44269504088896f;
#pragma unroll
  for (int nts = 0; nts < 4; ++nts) {
    float m = sa[0][nts][0];
#pragma unroll
    for (int mts = 0; mts < 4; ++mts)
#pragma unroll
      for (int r = 0; r < 4; ++r) m = fmaxf(m, sa[mts][nts][r]);
    m = fmaxf(m, __shfl_xor(m, 16));
    m = fmaxf(m, __shfl_xor(m, 32));
    float sum = 0.f;
#pragma unroll
    for (int mts = 0; mts < 4; ++mts)
#pragma unroll
      for (int r = 0; r < 4; ++r) {
        float p = __builtin_amdgcn_exp2f((sa[mts][nts][r] - m) * CEXP);
        sa[mts][nts][r] = p;
        sum += p;
      }
    sum += __shfl_xor(sum, 16);
    sum += __shfl_xor(sum, 32);
    float inv = __builtin_amdgcn_rcpf(sum);
#pragma unroll
    for (int ks = 0; ks < 2; ++ks) {
      short8 f;
#pragma unroll
      for (int e = 0; e < 4; ++e) {
        f[e]     = (short)f2bf(sa[2 * ks][nts][e] * inv);
        f[4 + e] = (short)f2bf(sa[2 * ks + 1][nts][e] * inv);
      }
      pf[nts][ks] = f;
    }
  }

  short8 vf[4][2];
  {
    floatx4 acc[4][4] = {};
#pragma unroll
    for (int kc = 0; kc < 8; ++kc) {
      short8 Av[4], Bv[4];
#pragma unroll
      for (int mt = 0; mt < 4; ++mt) Av[mt] = ldsfrag(srow(mt * 16 + l15), kc);
#pragma unroll
      for (int nt = 0; nt < 4; ++nt)
        Bv[nt] = wpfrag(wbf, 32 + head * 4 + nt, kc, lane);
#pragma unroll
      for (int mt = 0; mt < 4; ++mt)
#pragma unroll
        for (int nt = 0; nt < 4; ++nt)
          acc[mt][nt] = __builtin_amdgcn_mfma_f32_16x16x32_bf16(Av[mt], Bv[nt], acc[mt][nt], 0, 0, 0);
    }
#pragma unroll
    for (int nt = 0; nt < 4; ++nt)
#pragma unroll
      for (int ks = 0; ks < 2; ++ks) {
        short8 f;
#pragma unroll
        for (int e = 0; e < 4; ++e) {
          f[e]     = (short)f2bf(acc[2 * ks][nt][e]);
          f[4 + e] = (short)f2bf(acc[2 * ks + 1][nt][e]);
        }
        vf[nt][ks] = f;
      }
  }

  floatx4 oa[4][4] = {};
#pragma unroll
  for (int ks = 0; ks < 2; ++ks)
#pragma unroll
    for (int ntq = 0; ntq < 4; ++ntq)
#pragma unroll
      for (int dt = 0; dt < 4; ++dt)
        oa[ntq][dt] = __builtin_amdgcn_mfma_f32_16x16x32_bf16(pf[ntq][ks], vf[dt][ks], oa[ntq][dt], 0, 0, 0);

  __syncthreads();

#pragma unroll
  for (int ntq = 0; ntq < 4; ++ntq)
#pragma unroll
    for (int dt = 0; dt < 4; ++dt) {
      int c = head * 64 + dt * 16 + l15;
      int kc = c >> 5, hf = (c >> 4) & 1, gc = (c >> 2) & 3, e = c & 3;
#pragma unroll
      for (int r = 0; r < 4; ++r) {
        int tq = ntq * 16 + 4 * g + r;
        int sr = srow(tq);
        sxn[sr * 256 + (((kc * 4 + gc) ^ (sr & 7)) << 3) + hf * 4 + e] =
            f2bf(oa[ntq][dt][r]);
      }
    }
  __syncthreads();

  floatx4 fa[2][8] = {};
#pragma unroll
  for (int kc = 0; kc < 8; ++kc) {
    short8 Bv[8], Av[2];
#pragma unroll
    for (int nt = 0; nt < 8; ++nt) Bv[nt] = ldsfrag(nt * 16 + l15, kc);
#pragma unroll
    for (int mt = 0; mt < 2; ++mt)
      Av[mt] = wpfrag(wbf, 48 + wv * 2 + mt, kc, lane);
#pragma unroll
    for (int mt = 0; mt < 2; ++mt)
#pragma unroll
      for (int nt = 0; nt < 8; ++nt)
        fa[mt][nt] = __builtin_amdgcn_mfma_f32_16x16x32_bf16(Av[mt], Bv[nt], fa[mt][nt], 0, 0, 0);
  }

#pragma unroll
  for (int mt = 0; mt < 2; ++mt)
#pragma unroll
    for (int nt = 0; nt < 8; ++nt)
#pragma unroll
      for (int r = 0; r < 4; ++r) {
        int co = wv * 32 + mt * 16 + 4 * g + r;
        int tt = nt * 16 + l15;
        float val = fa[mt][nt][r] + bf2f(sres[ridx2(co, tt)]);
        out[((size_t)(b * 256 + co) << 16) + (size_t)(wy * 8 + (tt >> 4)) * 256 +
            (wxp * 16 + (tt & 15))] = val;
      }
}

extern "C" void kernel_launch(void* const* d_in, const int* in_sizes, int n_in,
                              void* d_out, int out_size, void* d_ws, size_t ws_size,
                              hipStream_t stream) {
  const float* x     = (const float*)d_in[0];
  const float* gamma = (const float*)d_in[1];
  const float* beta  = (const float*)d_in[2];
  const float* wqkv  = (const float*)d_in[3];
  const float* wout  = (const float*)d_in[4];
  float* out = (float*)d_out;

  unsigned short* wbf   = (unsigned short*)d_ws;             // 512 KB packed bf16 weights
  unsigned short* o_scr = wbf + 262144;                      // 128 MB o scratch
  unsigned short* frag  = o_scr + 67108864;                  // 384 MB qkv fragments

  const size_t need = 512 * 1024 + (size_t)128 * 1024 * 1024 + (size_t)384 * 1024 * 1024;

  wconv<<<128, 256, 0, stream>>>(wqkv, wout, wbf);
  if (ws_size >= need) {
    k1a_qkv<<<2048, 512, 0, stream>>>(x, gamma, beta, wbf, frag);
    k1b_attn<<<2048, 256, 0, stream>>>(frag, o_scr);
    k2_proj<<<1024, 512, 0, stream>>>(o_scr, x, wbf, out);
  } else {
    fused_fallback<<<2048, 512, 0, stream>>>(x, gamma, beta, wbf, out);
  }
}

// Round 16
// 484.222 us; speedup vs baseline: 1.3687x; 1.1463x over previous
//
#include <hip/hip_runtime.h>
#include <hip/hip_bf16.h>

typedef __attribute__((ext_vector_type(8))) short short8;
typedef __attribute__((ext_vector_type(4))) float floatx4;
typedef __attribute__((ext_vector_type(2))) float floatx2;
typedef __attribute__((ext_vector_type(4))) unsigned short ushort4v;

#define DEVI static __device__ __forceinline__

// native hardware RNE conversion (r15 lesson: hand-rolled 3-op bit math cost
// ~1000 VALU ops/thread in k1a; compiler emits v_cvt_pk_bf16_f32-class ops)
DEVI unsigned short f2bf(float f) {
  union { __hip_bfloat16 b; unsigned short u; } v;
  v.b = __float2bfloat16(f);
  return v.u;
}
DEVI float bf2f(unsigned short h) { return __uint_as_float(((unsigned int)h) << 16); }

// x staging LDS: [c][t] bf16, t in [0,128), swizzled
DEVI int ridx2(int c, int t) { return c * 128 + (t ^ ((c & 7) << 3)); }
// frag-order LDS: row in [0,128), 32 chunks of 8 bf16, chunk-swizzled
DEVI int xnaddr(int row, int chunk) { return row * 256 + (((chunk) ^ (row & 7)) << 3); }

// packed weight fragment: rb = 16-row tile (0..47 Wqkv, 48..63 Wout), kc = K/32.
DEVI short8 wpfrag(const unsigned short* __restrict__ wbf, int rb, int kc, int lane) {
  return *(const short8*)&wbf[(((size_t)rb * 8 + kc) * 64 + lane) * 8];
}

// ---------------- weight fp32 -> packed bf16 fragments ----------------
__global__ void wconv(const float* __restrict__ wqkv, const float* __restrict__ wout,
                      unsigned short* __restrict__ wbf) {
  int cl = blockIdx.x * 256 + threadIdx.x;   // 0..32767 (grid 128)
  int lane = cl & 63;
  int rbkc = cl >> 6;
  int kc = rbkc & 7;
  int rb = rbkc >> 3;                        // 0..63
  int g = lane >> 4, l15 = lane & 15;
  const float* src = (rb < 48) ? wqkv : wout;
  int row = (rb < 48) ? rb * 16 + l15 : (rb - 48) * 16 + l15;
#pragma unroll
  for (int h = 0; h < 2; ++h)
#pragma unroll
    for (int e = 0; e < 4; ++e)
      wbf[(size_t)cl * 8 + h * 4 + e] = f2bf(src[row * 256 + kc * 32 + h * 16 + g * 4 + e]);
}

// ================= k1a: LN + QKV GEMMs -> fragment scratch =================
// (512,2). r13-validated structure: Phase A staged float4 loads (r15 showed
// direct scalar-global LN loads regress 250->320us). Weight frags packed-
// coalesced + preloaded 4-kc deep (wreg) so the kc loop runs from regs+LDS.
__global__ __launch_bounds__(512, 2) void k1a_qkv(
    const float* __restrict__ x, const float* __restrict__ gamma,
    const float* __restrict__ beta, const unsigned short* __restrict__ wbf,
    unsigned short* __restrict__ frag) {
  __shared__ __align__(16) unsigned short sx[128 * 256];   // 64KB: x -> xn frags
  __shared__ floatx2 psum[4][128];                          // 4KB LN partials

  const int tid = threadIdx.x;
  const int lane = tid & 63;
  const int wv = tid >> 6;
  const int g = lane >> 4;
  const int l15 = lane & 15;

  // XCD-chunked swizzle (2048 blocks, 8 XCDs)
  const int id = ((blockIdx.x & 7) << 8) + (blockIdx.x >> 3);
  const int b = id >> 9;
  const int wy = (id >> 4) & 31;
  const int wxp = id & 15;
  const size_t xbase = ((size_t)b << 24) + (size_t)(wy * 8) * 256 + (size_t)(wxp * 16);

  // ---- Phase A: load x strip -> sx bf16 [c][t] ----
#pragma unroll
  for (int it = 0; it < 16; ++it) {
    int s = it * 512 + tid;
    int c = s >> 5, i = (s >> 2) & 7, j4 = s & 3;
    floatx4 v = *(const floatx4*)(x + xbase + (size_t)c * 65536 + i * 256 + j4 * 4);
    ushort4v u;
    u.x = f2bf(v.x); u.y = f2bf(v.y); u.z = f2bf(v.z); u.w = f2bf(v.w);
    *(ushort4v*)&sx[ridx2(c, i * 16 + j4 * 4)] = u;
  }
  __syncthreads();

  // ---- Phase B1: LN partials; 64 channels kept in regs ----
  const int t = tid & 127;
  const int q = tid >> 7;          // wave-uniform
  unsigned int xr[32];
  float s1 = 0.f, s2 = 0.f;
#pragma unroll
  for (int cc = 0; cc < 32; ++cc) {
    unsigned int u0 = sx[ridx2(q * 64 + 2 * cc, t)];
    unsigned int u1 = sx[ridx2(q * 64 + 2 * cc + 1, t)];
    xr[cc] = u0 | (u1 << 16);
    float a = __uint_as_float(u0 << 16);
    float c2 = __uint_as_float(u1 << 16);
    s1 += a + c2;
    s2 = fmaf(a, a, s2); s2 = fmaf(c2, c2, s2);
  }
  { floatx2 p; p.x = s1; p.y = s2; psum[q][t] = p; }
  __syncthreads();

  float S1 = 0.f, S2 = 0.f;
#pragma unroll
  for (int p = 0; p < 4; ++p) { floatx2 pp = psum[p][t]; S1 += pp.x; S2 += pp.y; }
  const float mu = S1 * (1.f / 256.f);
  const float rstd = rsqrtf(S2 * (1.f / 256.f) - mu * mu + 1e-5f);

  // ---- Phase B2: write xn bf16 in fragment order ----
#pragma unroll
  for (int kk = 0; kk < 2; ++kk) {
    int kc = q * 2 + kk;
#pragma unroll
    for (int gc = 0; gc < 4; ++gc) {
      short8 s8;
#pragma unroll
      for (int hf = 0; hf < 2; ++hf)
#pragma unroll
        for (int e = 0; e < 4; ++e) {
          int lc = kk * 32 + hf * 16 + gc * 4 + e;
          int c = q * 64 + lc;
          unsigned int u = xr[lc >> 1];
          float xv = __uint_as_float((lc & 1) ? (u & 0xffff0000u) : (u << 16));
          float val = (xv - mu) * rstd * gamma[c] + beta[c];
          s8[hf * 4 + e] = (short)f2bf(val);
        }
      *(short8*)&sx[xnaddr(t, kc * 4 + gc)] = s8;
    }
  }
  __syncthreads();

  auto ldsfrag = [&](int row, int kc) -> short8 {
    return *(const short8*)&sx[xnaddr(row, kc * 4 + g)];
  };

  const int head = wv >> 1;
  const int win = wv & 1;
  auto srow = [&](int tl) { return (((tl) >> 3) << 4) + win * 8 + ((tl) & 7); };

  // fragment scratch base for this (strip, head, win): 24 slots x 512 ushorts
  unsigned short* fr = frag + ((size_t)(id * 8 + wv) * 24) * 512 + (size_t)lane * 8;

  // ---- q^T, k^T GEMMs: stream fragments to scratch (slots 0..15) ----
#pragma unroll
  for (int qk = 0; qk < 2; ++qk) {
    floatx4 acc[4][4] = {};
    const int rbq = qk * 16 + head * 4;
#pragma unroll
    for (int kh = 0; kh < 2; ++kh) {
      short8 wreg[4][4];
#pragma unroll
      for (int kk = 0; kk < 4; ++kk)
#pragma unroll
        for (int mt = 0; mt < 4; ++mt)
          wreg[kk][mt] = wpfrag(wbf, rbq + mt, kh * 4 + kk, lane);
#pragma unroll
      for (int kk = 0; kk < 4; ++kk) {
        int kc = kh * 4 + kk;
        short8 Bv[4];
#pragma unroll
        for (int nt = 0; nt < 4; ++nt) Bv[nt] = ldsfrag(srow(nt * 16 + l15), kc);
#pragma unroll
        for (int mt = 0; mt < 4; ++mt)
#pragma unroll
          for (int nt = 0; nt < 4; ++nt)
            acc[mt][nt] = __builtin_amdgcn_mfma_f32_16x16x32_bf16(wreg[kk][mt], Bv[nt], acc[mt][nt], 0, 0, 0);
      }
    }
#pragma unroll
    for (int nt = 0; nt < 4; ++nt)
#pragma unroll
      for (int ks = 0; ks < 2; ++ks) {
        short8 f;
#pragma unroll
        for (int e = 0; e < 4; ++e) {
          f[e]     = (short)f2bf(acc[2 * ks][nt][e]);
          f[4 + e] = (short)f2bf(acc[2 * ks + 1][nt][e]);
        }
        *(short8*)&fr[(size_t)(qk * 8 + nt * 2 + ks) * 512] = f;
      }
  }

  // ---- v GEMM: stream fragments to scratch (slots 16..23) ----
  {
    floatx4 acc[4][4] = {};
#pragma unroll
    for (int kh = 0; kh < 2; ++kh) {
      short8 wreg[4][4];
#pragma unroll
      for (int kk = 0; kk < 4; ++kk)
#pragma unroll
        for (int nt = 0; nt < 4; ++nt)
          wreg[kk][nt] = wpfrag(wbf, 32 + head * 4 + nt, kh * 4 + kk, lane);
#pragma unroll
      for (int kk = 0; kk < 4; ++kk) {
        int kc = kh * 4 + kk;
        short8 Av[4];
#pragma unroll
        for (int mt = 0; mt < 4; ++mt) Av[mt] = ldsfrag(srow(mt * 16 + l15), kc);
#pragma unroll
        for (int mt = 0; mt < 4; ++mt)
#pragma unroll
          for (int nt = 0; nt < 4; ++nt)
            acc[mt][nt] = __builtin_amdgcn_mfma_f32_16x16x32_bf16(Av[mt], wreg[kk][nt], acc[mt][nt], 0, 0, 0);
      }
    }
#pragma unroll
    for (int nt = 0; nt < 4; ++nt)
#pragma unroll
      for (int ks = 0; ks < 2; ++ks) {
        short8 f;
#pragma unroll
        for (int e = 0; e < 4; ++e) {
          f[e]     = (short)f2bf(acc[2 * ks][nt][e]);
          f[4 + e] = (short)f2bf(acc[2 * ks + 1][nt][e]);
        }
        *(short8*)&fr[(size_t)(16 + nt * 2 + ks) * 512] = f;
      }
  }
}

// ================= k1b: pure-register window attention =====================
__global__ __launch_bounds__(256, 1) void k1b_attn(
    const unsigned short* __restrict__ frag, unsigned short* __restrict__ o_scr) {
  const int tid = threadIdx.x;
  const int lane = tid & 63;
  const int head = tid >> 6;       // 0..3
  const int g = lane >> 4;
  const int l15 = lane & 15;

  const int id = ((blockIdx.x & 7) << 8) + (blockIdx.x >> 3);
  const int b = id >> 9;
  const int wy = (id >> 4) & 31;
  const int wxp = id & 15;

  const float CEXP = 0.125f * 1.44269504088896f;

#pragma unroll 1
  for (int win = 0; win < 2; ++win) {
    const unsigned short* fr =
        frag + ((size_t)(id * 8 + head * 2 + win) * 24) * 512 + (size_t)lane * 8;

    short8 qkf[2][4][2];
#pragma unroll
    for (int qk = 0; qk < 2; ++qk)
#pragma unroll
      for (int nt = 0; nt < 4; ++nt)
#pragma unroll
        for (int ks = 0; ks < 2; ++ks)
          qkf[qk][nt][ks] = *(const short8*)&fr[(size_t)(qk * 8 + nt * 2 + ks) * 512];

    // ---- streamed S^T + softmax per q-tile ----
    short8 pf[4][2];
#pragma unroll
    for (int nts = 0; nts < 4; ++nts) {
      floatx4 sac[4] = {};
#pragma unroll
      for (int ks = 0; ks < 2; ++ks)
#pragma unroll
        for (int mts = 0; mts < 4; ++mts)
          sac[mts] = __builtin_amdgcn_mfma_f32_16x16x32_bf16(qkf[1][mts][ks], qkf[0][nts][ks], sac[mts], 0, 0, 0);

      float m = sac[0][0];
#pragma unroll
      for (int mts = 0; mts < 4; ++mts)
#pragma unroll
        for (int r = 0; r < 4; ++r) m = fmaxf(m, sac[mts][r]);
      m = fmaxf(m, __shfl_xor(m, 16));
      m = fmaxf(m, __shfl_xor(m, 32));
      float sum = 0.f;
#pragma unroll
      for (int mts = 0; mts < 4; ++mts)
#pragma unroll
        for (int r = 0; r < 4; ++r) {
          float p = __builtin_amdgcn_exp2f((sac[mts][r] - m) * CEXP);
          sac[mts][r] = p;
          sum += p;
        }
      sum += __shfl_xor(sum, 16);
      sum += __shfl_xor(sum, 32);
      float inv = __builtin_amdgcn_rcpf(sum);
#pragma unroll
      for (int ks = 0; ks < 2; ++ks) {
        short8 f;
#pragma unroll
        for (int e = 0; e < 4; ++e) {
          f[e]     = (short)f2bf(sac[2 * ks][e] * inv);
          f[4 + e] = (short)f2bf(sac[2 * ks + 1][e] * inv);
        }
        pf[nts][ks] = f;
      }
    }

    // ---- v fragments ----
    short8 vf[4][2];
#pragma unroll
    for (int nt = 0; nt < 4; ++nt)
#pragma unroll
      for (int ks = 0; ks < 2; ++ks)
        vf[nt][ks] = *(const short8*)&fr[(size_t)(16 + nt * 2 + ks) * 512];

    // ---- O^T = mfma(vf, pf); direct coalesced o_scr store ----
    floatx4 oa2[4][4];   // [dt][ntq]
#pragma unroll
    for (int dt = 0; dt < 4; ++dt)
#pragma unroll
      for (int ntq = 0; ntq < 4; ++ntq) oa2[dt][ntq] = floatx4{0.f, 0.f, 0.f, 0.f};
#pragma unroll
    for (int ks = 0; ks < 2; ++ks)
#pragma unroll
      for (int dt = 0; dt < 4; ++dt)
#pragma unroll
        for (int ntq = 0; ntq < 4; ++ntq)
          oa2[dt][ntq] = __builtin_amdgcn_mfma_f32_16x16x32_bf16(vf[dt][ks], pf[ntq][ks], oa2[dt][ntq], 0, 0, 0);

#pragma unroll
    for (int dtp = 0; dtp < 2; ++dtp)
#pragma unroll
      for (int ntq = 0; ntq < 4; ++ntq) {
        int tq = ntq * 16 + l15;
        size_t orow = ((size_t)b * 256 + wy * 8 + (tq >> 3)) * 256 + wxp * 16 + win * 8 + (tq & 7);
        short8 o8;
#pragma unroll
        for (int r = 0; r < 4; ++r) {
          o8[r]     = (short)f2bf(oa2[2 * dtp][ntq][r]);
          o8[4 + r] = (short)f2bf(oa2[2 * dtp + 1][ntq][r]);
        }
        *(short8*)&o_scr[orow * 256 + head * 64 + dtp * 32 + g * 8] = o8;
      }
  }
}

// ================= k2: out-proj + residual, NCHW float4 epilogue ==========
__global__ __launch_bounds__(512, 2) void k2_proj(
    const unsigned short* __restrict__ o_scr, const float* __restrict__ x,
    const unsigned short* __restrict__ wbf, float* __restrict__ out) {
  __shared__ __align__(16) unsigned short sx[128 * 256];   // 64KB o-frag staging

  const int tid = threadIdx.x;
  const int lane = tid & 63;
  const int wv = tid >> 6;
  const int g = lane >> 4;
  const int l15 = lane & 15;

  const int b = blockIdx.x >> 8;
  const int h = blockIdx.x & 255;

  auto ldsfrag = [&](int row, int kc) -> short8 {
    return *(const short8*)&sx[xnaddr(row, kc * 4 + g)];
  };

#pragma unroll
  for (int hf = 0; hf < 2; ++hf) {
    const size_t obase = (((size_t)b * 256 + h) * 256 + hf * 128) * 256;
#pragma unroll
    for (int it = 0; it < 8; ++it) {
      int s = it * 512 + tid;
      int tl = s >> 5, cid = s & 31;
      short8 v = *(const short8*)&o_scr[obase + tl * 256 + cid * 8];
      *(short8*)&sx[tl * 256 + ((cid ^ (tl & 7)) << 3)] = v;
    }
    __syncthreads();

    floatx4 fa[8][2] = {};   // [nt = token tile][mt = co tile]
#pragma unroll
    for (int kc = 0; kc < 8; ++kc) {
      short8 Atok[8], Bw[2];
#pragma unroll
      for (int nt = 0; nt < 8; ++nt) Atok[nt] = ldsfrag(nt * 16 + l15, kc);
#pragma unroll
      for (int mt = 0; mt < 2; ++mt)
        Bw[mt] = wpfrag(wbf, 48 + wv * 2 + mt, kc, lane);
#pragma unroll
      for (int nt = 0; nt < 8; ++nt)
#pragma unroll
        for (int mt = 0; mt < 2; ++mt)
          fa[nt][mt] = __builtin_amdgcn_mfma_f32_16x16x32_bf16(Atok[nt], Bw[mt], fa[nt][mt], 0, 0, 0);
    }

    // epilogue: lane holds 4 consecutive w (row = 4g+r) for one co (col = l15)
#pragma unroll
    for (int nt = 0; nt < 8; ++nt)
#pragma unroll
      for (int mt = 0; mt < 2; ++mt) {
        int co = wv * 32 + mt * 16 + l15;
        size_t addr = (((size_t)(b * 256 + co)) << 16) + (size_t)h * 256 +
                      hf * 128 + nt * 16 + 4 * g;
        floatx4 xv = *(const floatx4*)(x + addr);
        floatx4 o;
#pragma unroll
        for (int r = 0; r < 4; ++r) o[r] = fa[nt][mt][r] + xv[r];
        *(floatx4*)(out + addr) = o;
      }
    __syncthreads();
  }
}

// ================= fallback (fused, r13 form) if d_ws too small ============
__global__ __launch_bounds__(512, 2) void fused_fallback(
    const float* __restrict__ x, const float* __restrict__ gamma,
    const float* __restrict__ beta, const unsigned short* __restrict__ wbf,
    float* __restrict__ out) {
  __shared__ __align__(16) unsigned short sres[256 * 128];
  __shared__ __align__(16) unsigned short sxn[128 * 256];

  const int tid = threadIdx.x;
  const int lane = tid & 63;
  const int wv = tid >> 6;
  const int g = lane >> 4;
  const int l15 = lane & 15;

  const int id = ((blockIdx.x & 7) << 8) + (blockIdx.x >> 3);
  const int b = id >> 9;
  const int wy = (id >> 4) & 31;
  const int wxp = id & 15;
  const size_t xbase = ((size_t)b << 24) + (size_t)(wy * 8) * 256 + (size_t)(wxp * 16);

#pragma unroll
  for (int it = 0; it < 16; ++it) {
    int s = it * 512 + tid;
    int c = s >> 5, i = (s >> 2) & 7, j4 = s & 3;
    floatx4 v = *(const floatx4*)(x + xbase + (size_t)c * 65536 + i * 256 + j4 * 4);
    ushort4v u;
    u.x = f2bf(v.x); u.y = f2bf(v.y); u.z = f2bf(v.z); u.w = f2bf(v.w);
    *(ushort4v*)&sres[ridx2(c, i * 16 + j4 * 4)] = u;
  }
  __syncthreads();

  const int t = tid & 127;
  const int q = tid >> 7;
  float s1 = 0.f, s2 = 0.f;
#pragma unroll 8
  for (int cc = 0; cc < 64; ++cc) {
    float xv = bf2f(sres[ridx2(q * 64 + cc, t)]);
    s1 += xv; s2 += xv * xv;
  }
  { floatx2 p; p.x = s1; p.y = s2; ((floatx2*)sxn)[q * 128 + t] = p; }
  __syncthreads();

  float S1 = 0.f, S2 = 0.f;
#pragma unroll
  for (int p = 0; p < 4; ++p) {
    floatx2 pp = ((const floatx2*)sxn)[p * 128 + t];
    S1 += pp.x; S2 += pp.y;
  }
  const float mu = S1 * (1.f / 256.f);
  const float rstd = rsqrtf(S2 * (1.f / 256.f) - mu * mu + 1e-5f);
  __syncthreads();

#pragma unroll
  for (int kk = 0; kk < 2; ++kk) {
    int kc = q * 2 + kk;
#pragma unroll
    for (int gc = 0; gc < 4; ++gc) {
      short8 s8;
#pragma unroll
      for (int hf = 0; hf < 2; ++hf)
#pragma unroll
        for (int e = 0; e < 4; ++e) {
          int c = kc * 32 + hf * 16 + gc * 4 + e;
          float xv = bf2f(sres[ridx2(c, t)]);
          float val = (xv - mu) * rstd * gamma[c] + beta[c];
          s8[hf * 4 + e] = (short)f2bf(val);
        }
      *(short8*)&sxn[xnaddr(t, kc * 4 + gc)] = s8;
    }
  }
  __syncthreads();

  auto ldsfrag = [&](int row, int kc) -> short8 {
    return *(const short8*)&sxn[xnaddr(row, kc * 4 + g)];
  };

  const int head = wv >> 1;
  const int win = wv & 1;
  auto srow = [&](int tl) { return (((tl) >> 3) << 4) + win * 8 + ((tl) & 7); };

  short8 qkf[2][4][2];
#pragma unroll
  for (int qk = 0; qk < 2; ++qk) {
    floatx4 acc[4][4] = {};
    const int rbq = qk * 16 + head * 4;
#pragma unroll
    for (int kc = 0; kc < 8; ++kc) {
      short8 Bv[4], Av[4];
#pragma unroll
      for (int nt = 0; nt < 4; ++nt) Bv[nt] = ldsfrag(srow(nt * 16 + l15), kc);
#pragma unroll
      for (int mt = 0; mt < 4; ++mt)
        Av[mt] = wpfrag(wbf, rbq + mt, kc, lane);
#pragma unroll
      for (int mt = 0; mt < 4; ++mt)
#pragma unroll
        for (int nt = 0; nt < 4; ++nt)
          acc[mt][nt] = __builtin_amdgcn_mfma_f32_16x16x32_bf16(Av[mt], Bv[nt], acc[mt][nt], 0, 0, 0);
    }
#pragma unroll
    for (int nt = 0; nt < 4; ++nt)
#pragma unroll
      for (int ks = 0; ks < 2; ++ks) {
        short8 f;
#pragma unroll
        for (int e = 0; e < 4; ++e) {
          f[e]     = (short)f2bf(acc[2 * ks][nt][e]);
          f[4 + e] = (short)f2bf(acc[2 * ks + 1][nt][e]);
        }
        qkf[qk][nt][ks] = f;
      }
  }

  floatx4 sa[4][4] = {};
#pragma unroll
  for (int ks = 0; ks < 2; ++ks)
#pragma unroll
    for (int mts = 0; mts < 4; ++mts)
#pragma unroll
      for (int nts = 0; nts < 4; ++nts)
        sa[mts][nts] = __builtin_amdgcn_mfma_f32_16x16x32_bf16(qkf[1][mts][ks], qkf[0][nts][ks], sa[mts][nts], 0, 0, 0);

  short8 pf[4][2];
  const float CEXP = 0.125f * 1.44269504088896f;
#pragma unroll
  for (int nts = 0; nts < 4; ++nts) {
    float m = sa[0][nts][0];
#pragma unroll
    for (int mts = 0; mts < 4; ++mts)
#pragma unroll
      for (int r = 0; r < 4; ++r) m = fmaxf(m, sa[mts][nts][r]);
    m = fmaxf(m, __shfl_xor(m, 16));
    m = fmaxf(m, __shfl_xor(m, 32));
    float sum = 0.f;
#pragma unroll
    for (int mts = 0; mts < 4; ++mts)
#pragma unroll
      for (int r = 0; r < 4; ++r) {
        float p = __builtin_amdgcn_exp2f((sa[mts][nts][r] - m) * CEXP);
        sa[mts][nts][r] = p;
        sum += p;
      }
    sum += __shfl_xor(sum, 16);
    sum += __shfl_xor(sum, 32);
    float inv = __builtin_amdgcn_rcpf(sum);
#pragma unroll
    for (int ks = 0; ks < 2; ++ks) {
      short8 f;
#pragma unroll
      for (int e = 0; e < 4; ++e) {
        f[e]     = (short)f2bf(sa[2 * ks][nts][e] * inv);
        f[4 + e] = (short)f2bf(sa[2 * ks + 1][nts][e] * inv);
      }
      pf[nts][ks] = f;
    }
  }

  short8 vf[4][2];
  {
    floatx4 acc[4][4] = {};
#pragma unroll
    for (int kc = 0; kc < 8; ++kc) {
      short8 Av[4], Bv[4];
#pragma unroll
      for (int mt = 0; mt < 4; ++mt) Av[mt] = ldsfrag(srow(mt * 16 + l15), kc);
#pragma unroll
      for (int nt = 0; nt < 4; ++nt)
        Bv[nt] = wpfrag(wbf, 32 + head * 4 + nt, kc, lane);
#pragma unroll
      for (int mt = 0; mt < 4; ++mt)
#pragma unroll
        for (int nt = 0; nt < 4; ++nt)
          acc[mt][nt] = __builtin_amdgcn_mfma_f32_16x16x32_bf16(Av[mt], Bv[nt], acc[mt][nt], 0, 0, 0);
    }
#pragma unroll
    for (int nt = 0; nt < 4; ++nt)
#pragma unroll
      for (int ks = 0; ks < 2; ++ks) {
        short8 f;
#pragma unroll
        for (int e = 0; e < 4; ++e) {
          f[e]     = (short)f2bf(acc[2 * ks][nt][e]);
          f[4 + e] = (short)f2bf(acc[2 * ks + 1][nt][e]);
        }
        vf[nt][ks] = f;
      }
  }

  floatx4 oa[4][4] = {};
#pragma unroll
  for (int ks = 0; ks < 2; ++ks)
#pragma unroll
    for (int ntq = 0; ntq < 4; ++ntq)
#pragma unroll
      for (int dt = 0; dt < 4; ++dt)
        oa[ntq][dt] = __builtin_amdgcn_mfma_f32_16x16x32_bf16(pf[ntq][ks], vf[dt][ks], oa[ntq][dt], 0, 0, 0);

  __syncthreads();

#pragma unroll
  for (int ntq = 0; ntq < 4; ++ntq)
#pragma unroll
    for (int dt = 0; dt < 4; ++dt) {
      int c = head * 64 + dt * 16 + l15;
      int kc = c >> 5, hf = (c >> 4) & 1, gc = (c >> 2) & 3, e = c & 3;
#pragma unroll
      for (int r = 0; r < 4; ++r) {
        int tq = ntq * 16 + 4 * g + r;
        int sr = srow(tq);
        sxn[sr * 256 + (((kc * 4 + gc) ^ (sr & 7)) << 3) + hf * 4 + e] =
            f2bf(oa[ntq][dt][r]);
      }
    }
  __syncthreads();

  floatx4 fa[2][8] = {};
#pragma unroll
  for (int kc = 0; kc < 8; ++kc) {
    short8 Bv[8], Av[2];
#pragma unroll
    for (int nt = 0; nt < 8; ++nt) Bv[nt] = ldsfrag(nt * 16 + l15, kc);
#pragma unroll
    for (int mt = 0; mt < 2; ++mt)
      Av[mt] = wpfrag(wbf, 48 + wv * 2 + mt, kc, lane);
#pragma unroll
    for (int mt = 0; mt < 2; ++mt)
#pragma unroll
      for (int nt = 0; nt < 8; ++nt)
        fa[mt][nt] = __builtin_amdgcn_mfma_f32_16x16x32_bf16(Av[mt], Bv[nt], fa[mt][nt], 0, 0, 0);
  }

#pragma unroll
  for (int mt = 0; mt < 2; ++mt)
#pragma unroll
    for (int nt = 0; nt < 8; ++nt)
#pragma unroll
      for (int r = 0; r < 4; ++r) {
        int co = wv * 32 + mt * 16 + 4 * g + r;
        int tt = nt * 16 + l15;
        float val = fa[mt][nt][r] + bf2f(sres[ridx2(co, tt)]);
        out[((size_t)(b * 256 + co) << 16) + (size_t)(wy * 8 + (tt >> 4)) * 256 +
            (wxp * 16 + (tt & 15))] = val;
      }
}

extern "C" void kernel_launch(void* const* d_in, const int* in_sizes, int n_in,
                              void* d_out, int out_size, void* d_ws, size_t ws_size,
                              hipStream_t stream) {
  const float* x     = (const float*)d_in[0];
  const float* gamma = (const float*)d_in[1];
  const float* beta  = (const float*)d_in[2];
  const float* wqkv  = (const float*)d_in[3];
  const float* wout  = (const float*)d_in[4];
  float* out = (float*)d_out;

  unsigned short* wbf   = (unsigned short*)d_ws;             // 512 KB packed bf16 weights
  unsigned short* o_scr = wbf + 262144;                      // 128 MB o scratch
  unsigned short* frag  = o_scr + 67108864;                  // 384 MB qkv fragments

  const size_t need = 512 * 1024 + (size_t)128 * 1024 * 1024 + (size_t)384 * 1024 * 1024;

  wconv<<<128, 256, 0, stream>>>(wqkv, wout, wbf);
  if (ws_size >= need) {
    k1a_qkv<<<2048, 512, 0, stream>>>(x, gamma, beta, wbf, frag);
    k1b_attn<<<2048, 256, 0, stream>>>(frag, o_scr);
    k2_proj<<<1024, 512, 0, stream>>>(o_scr, x, wbf, out);
  } else {
    fused_fallback<<<2048, 512, 0, stream>>>(x, gamma, beta, wbf, out);
  }
}

// Round 17
// 480.353 us; speedup vs baseline: 1.3797x; 1.0081x over previous
//
#include <hip/hip_runtime.h>
#include <hip/hip_bf16.h>

typedef __attribute__((ext_vector_type(8))) short short8;
typedef __attribute__((ext_vector_type(4))) float floatx4;
typedef __attribute__((ext_vector_type(2))) float floatx2;
typedef __attribute__((ext_vector_type(4))) unsigned short ushort4v;

#define DEVI static __device__ __forceinline__

// native hardware RNE conversion (r16: VALUBusy 20.8 -> 14.1%)
DEVI unsigned short f2bf(float f) {
  union { __hip_bfloat16 b; unsigned short u; } v;
  v.b = __float2bfloat16(f);
  return v.u;
}
DEVI float bf2f(unsigned short h) { return __uint_as_float(((unsigned int)h) << 16); }

// x staging LDS: [c][t] bf16, t in [0,128), swizzled
DEVI int ridx2(int c, int t) { return c * 128 + (t ^ ((c & 7) << 3)); }
// frag-order LDS: row in [0,128), 32 chunks of 8 bf16, chunk-swizzled
DEVI int xnaddr(int row, int chunk) { return row * 256 + (((chunk) ^ (row & 7)) << 3); }

// packed weight fragment: rb = 16-row tile (0..47 Wqkv, 48..63 Wout), kc = K/32.
DEVI short8 wpfrag(const unsigned short* __restrict__ wbf, int rb, int kc, int lane) {
  return *(const short8*)&wbf[(((size_t)rb * 8 + kc) * 64 + lane) * 8];
}

// ---------------- weight fp32 -> packed bf16 fragments ----------------
__global__ void wconv(const float* __restrict__ wqkv, const float* __restrict__ wout,
                      unsigned short* __restrict__ wbf) {
  int cl = blockIdx.x * 256 + threadIdx.x;   // 0..32767 (grid 128)
  int lane = cl & 63;
  int rbkc = cl >> 6;
  int kc = rbkc & 7;
  int rb = rbkc >> 3;                        // 0..63
  int g = lane >> 4, l15 = lane & 15;
  const float* src = (rb < 48) ? wqkv : wout;
  int row = (rb < 48) ? rb * 16 + l15 : (rb - 48) * 16 + l15;
#pragma unroll
  for (int h = 0; h < 2; ++h)
#pragma unroll
    for (int e = 0; e < 4; ++e)
      wbf[(size_t)cl * 8 + h * 4 + e] = f2bf(src[row * 256 + kc * 32 + h * 16 + g * 4 + e]);
}

// ======== k1: LN + QKV GEMMs + window attention -> o_scr (fused) ==========
// (512,2). r17 re-fusion: packed weights (r11) + native cvt (r16) removed the
// address/temp register pressure that made r5-r8's fused attempts spill.
// wreg depth 2 (not 4) keeps peak live ~200 < 256-reg budget. Spill check:
// WRITE must be ~134MB (o_scr only).
__global__ __launch_bounds__(512, 2) void k1_fused(
    const float* __restrict__ x, const float* __restrict__ gamma,
    const float* __restrict__ beta, const unsigned short* __restrict__ wbf,
    unsigned short* __restrict__ o_scr) {
  __shared__ __align__(16) unsigned short sx[128 * 256];   // 64KB: x -> xn frags
  __shared__ floatx2 psum[4][128];                          // 4KB LN partials

  const int tid = threadIdx.x;
  const int lane = tid & 63;
  const int wv = tid >> 6;
  const int g = lane >> 4;
  const int l15 = lane & 15;

  // XCD-chunked swizzle (2048 blocks, 8 XCDs)
  const int id = ((blockIdx.x & 7) << 8) + (blockIdx.x >> 3);
  const int b = id >> 9;
  const int wy = (id >> 4) & 31;
  const int wxp = id & 15;
  const size_t xbase = ((size_t)b << 24) + (size_t)(wy * 8) * 256 + (size_t)(wxp * 16);

  // ---- Phase A: load x strip -> sx bf16 [c][t] ----
#pragma unroll
  for (int it = 0; it < 16; ++it) {
    int s = it * 512 + tid;
    int c = s >> 5, i = (s >> 2) & 7, j4 = s & 3;
    floatx4 v = *(const floatx4*)(x + xbase + (size_t)c * 65536 + i * 256 + j4 * 4);
    ushort4v u;
    u.x = f2bf(v.x); u.y = f2bf(v.y); u.z = f2bf(v.z); u.w = f2bf(v.w);
    *(ushort4v*)&sx[ridx2(c, i * 16 + j4 * 4)] = u;
  }
  __syncthreads();

  // ---- Phase B1: LN partials; 64 channels kept in regs ----
  const int t = tid & 127;
  const int q = tid >> 7;          // wave-uniform
  unsigned int xr[32];
  float s1 = 0.f, s2 = 0.f;
#pragma unroll
  for (int cc = 0; cc < 32; ++cc) {
    unsigned int u0 = sx[ridx2(q * 64 + 2 * cc, t)];
    unsigned int u1 = sx[ridx2(q * 64 + 2 * cc + 1, t)];
    xr[cc] = u0 | (u1 << 16);
    float a = __uint_as_float(u0 << 16);
    float c2 = __uint_as_float(u1 << 16);
    s1 += a + c2;
    s2 = fmaf(a, a, s2); s2 = fmaf(c2, c2, s2);
  }
  { floatx2 p; p.x = s1; p.y = s2; psum[q][t] = p; }
  __syncthreads();

  float S1 = 0.f, S2 = 0.f;
#pragma unroll
  for (int p = 0; p < 4; ++p) { floatx2 pp = psum[p][t]; S1 += pp.x; S2 += pp.y; }
  const float mu = S1 * (1.f / 256.f);
  const float rstd = rsqrtf(S2 * (1.f / 256.f) - mu * mu + 1e-5f);

  // ---- Phase B2: write xn bf16 in fragment order ----
#pragma unroll
  for (int kk = 0; kk < 2; ++kk) {
    int kc = q * 2 + kk;
#pragma unroll
    for (int gc = 0; gc < 4; ++gc) {
      short8 s8;
#pragma unroll
      for (int hf = 0; hf < 2; ++hf)
#pragma unroll
        for (int e = 0; e < 4; ++e) {
          int lc = kk * 32 + hf * 16 + gc * 4 + e;
          int c = q * 64 + lc;
          unsigned int u = xr[lc >> 1];
          float xv = __uint_as_float((lc & 1) ? (u & 0xffff0000u) : (u << 16));
          float val = (xv - mu) * rstd * gamma[c] + beta[c];
          s8[hf * 4 + e] = (short)f2bf(val);
        }
      *(short8*)&sx[xnaddr(t, kc * 4 + gc)] = s8;
    }
  }
  __syncthreads();

  auto ldsfrag = [&](int row, int kc) -> short8 {
    return *(const short8*)&sx[xnaddr(row, kc * 4 + g)];
  };

  const int head = wv >> 1;
  const int win = wv & 1;
  auto srow = [&](int tl) { return (((tl) >> 3) << 4) + win * 8 + ((tl) & 7); };

  const float CEXP = 0.125f * 1.44269504088896f;

  // ---- Q GEMM -> qf ----
  short8 qf[4][2], kf[4][2];
#pragma unroll
  for (int qk = 0; qk < 2; ++qk) {
    floatx4 acc[4][4] = {};
    const int rbq = qk * 16 + head * 4;
#pragma unroll
    for (int kh = 0; kh < 4; ++kh) {         // wreg depth 2
      short8 wreg[2][4];
#pragma unroll
      for (int kk = 0; kk < 2; ++kk)
#pragma unroll
        for (int mt = 0; mt < 4; ++mt)
          wreg[kk][mt] = wpfrag(wbf, rbq + mt, kh * 2 + kk, lane);
#pragma unroll
      for (int kk = 0; kk < 2; ++kk) {
        int kc = kh * 2 + kk;
        short8 Bv[4];
#pragma unroll
        for (int nt = 0; nt < 4; ++nt) Bv[nt] = ldsfrag(srow(nt * 16 + l15), kc);
#pragma unroll
        for (int mt = 0; mt < 4; ++mt)
#pragma unroll
          for (int nt = 0; nt < 4; ++nt)
            acc[mt][nt] = __builtin_amdgcn_mfma_f32_16x16x32_bf16(wreg[kk][mt], Bv[nt], acc[mt][nt], 0, 0, 0);
      }
    }
#pragma unroll
    for (int nt = 0; nt < 4; ++nt)
#pragma unroll
      for (int ks = 0; ks < 2; ++ks) {
        short8 f;
#pragma unroll
        for (int e = 0; e < 4; ++e) {
          f[e]     = (short)f2bf(acc[2 * ks][nt][e]);
          f[4 + e] = (short)f2bf(acc[2 * ks + 1][nt][e]);
        }
        if (qk == 0) qf[nt][ks] = f; else kf[nt][ks] = f;
      }
  }

  // ---- streamed S^T + softmax per q-tile -> pf (qf,kf die after) ----
  short8 pf[4][2];
#pragma unroll
  for (int nts = 0; nts < 4; ++nts) {
    floatx4 sac[4] = {};
#pragma unroll
    for (int ks = 0; ks < 2; ++ks)
#pragma unroll
      for (int mts = 0; mts < 4; ++mts)
        sac[mts] = __builtin_amdgcn_mfma_f32_16x16x32_bf16(kf[mts][ks], qf[nts][ks], sac[mts], 0, 0, 0);

    float m = sac[0][0];
#pragma unroll
    for (int mts = 0; mts < 4; ++mts)
#pragma unroll
      for (int r = 0; r < 4; ++r) m = fmaxf(m, sac[mts][r]);
    m = fmaxf(m, __shfl_xor(m, 16));
    m = fmaxf(m, __shfl_xor(m, 32));
    float sum = 0.f;
#pragma unroll
    for (int mts = 0; mts < 4; ++mts)
#pragma unroll
      for (int r = 0; r < 4; ++r) {
        float p = __builtin_amdgcn_exp2f((sac[mts][r] - m) * CEXP);
        sac[mts][r] = p;
        sum += p;
      }
    sum += __shfl_xor(sum, 16);
    sum += __shfl_xor(sum, 32);
    float inv = __builtin_amdgcn_rcpf(sum);
#pragma unroll
    for (int ks = 0; ks < 2; ++ks) {
      short8 f;
#pragma unroll
      for (int e = 0; e < 4; ++e) {
        f[e]     = (short)f2bf(sac[2 * ks][e] * inv);
        f[4 + e] = (short)f2bf(sac[2 * ks + 1][e] * inv);
      }
      pf[nts][ks] = f;
    }
  }

  // ---- V GEMM -> vf (only pf co-lives) ----
  short8 vf[4][2];
  {
    floatx4 acc[4][4] = {};
#pragma unroll
    for (int kh = 0; kh < 4; ++kh) {         // wreg depth 2
      short8 wreg[2][4];
#pragma unroll
      for (int kk = 0; kk < 2; ++kk)
#pragma unroll
        for (int nt = 0; nt < 4; ++nt)
          wreg[kk][nt] = wpfrag(wbf, 32 + head * 4 + nt, kh * 2 + kk, lane);
#pragma unroll
      for (int kk = 0; kk < 2; ++kk) {
        int kc = kh * 2 + kk;
        short8 Av[4];
#pragma unroll
        for (int mt = 0; mt < 4; ++mt) Av[mt] = ldsfrag(srow(mt * 16 + l15), kc);
#pragma unroll
        for (int mt = 0; mt < 4; ++mt)
#pragma unroll
          for (int nt = 0; nt < 4; ++nt)
            acc[mt][nt] = __builtin_amdgcn_mfma_f32_16x16x32_bf16(Av[mt], wreg[kk][nt], acc[mt][nt], 0, 0, 0);
      }
    }
#pragma unroll
    for (int nt = 0; nt < 4; ++nt)
#pragma unroll
      for (int ks = 0; ks < 2; ++ks) {
        short8 f;
#pragma unroll
        for (int e = 0; e < 4; ++e) {
          f[e]     = (short)f2bf(acc[2 * ks][nt][e]);
          f[4 + e] = (short)f2bf(acc[2 * ks + 1][nt][e]);
        }
        vf[nt][ks] = f;
      }
  }

  // ---- O^T = mfma(vf, pf); direct coalesced o_scr store ----
  floatx4 oa2[4][4];   // [dt][ntq]
#pragma unroll
  for (int dt = 0; dt < 4; ++dt)
#pragma unroll
    for (int ntq = 0; ntq < 4; ++ntq) oa2[dt][ntq] = floatx4{0.f, 0.f, 0.f, 0.f};
#pragma unroll
  for (int ks = 0; ks < 2; ++ks)
#pragma unroll
    for (int dt = 0; dt < 4; ++dt)
#pragma unroll
      for (int ntq = 0; ntq < 4; ++ntq)
        oa2[dt][ntq] = __builtin_amdgcn_mfma_f32_16x16x32_bf16(vf[dt][ks], pf[ntq][ks], oa2[dt][ntq], 0, 0, 0);

#pragma unroll
  for (int dtp = 0; dtp < 2; ++dtp)
#pragma unroll
    for (int ntq = 0; ntq < 4; ++ntq) {
      int tq = ntq * 16 + l15;
      size_t orow = ((size_t)b * 256 + wy * 8 + (tq >> 3)) * 256 + wxp * 16 + win * 8 + (tq & 7);
      short8 o8;
#pragma unroll
      for (int r = 0; r < 4; ++r) {
        o8[r]     = (short)f2bf(oa2[2 * dtp][ntq][r]);
        o8[4 + r] = (short)f2bf(oa2[2 * dtp + 1][ntq][r]);
      }
      *(short8*)&o_scr[orow * 256 + head * 64 + dtp * 32 + g * 8] = o8;
    }
}

// ================= k2: out-proj + residual, NCHW float4 epilogue ==========
__global__ __launch_bounds__(512, 2) void k2_proj(
    const unsigned short* __restrict__ o_scr, const float* __restrict__ x,
    const unsigned short* __restrict__ wbf, float* __restrict__ out) {
  __shared__ __align__(16) unsigned short sx[128 * 256];   // 64KB o-frag staging

  const int tid = threadIdx.x;
  const int lane = tid & 63;
  const int wv = tid >> 6;
  const int g = lane >> 4;
  const int l15 = lane & 15;

  const int b = blockIdx.x >> 8;
  const int h = blockIdx.x & 255;

  auto ldsfrag = [&](int row, int kc) -> short8 {
    return *(const short8*)&sx[xnaddr(row, kc * 4 + g)];
  };

#pragma unroll
  for (int hf = 0; hf < 2; ++hf) {
    const size_t obase = (((size_t)b * 256 + h) * 256 + hf * 128) * 256;
#pragma unroll
    for (int it = 0; it < 8; ++it) {
      int s = it * 512 + tid;
      int tl = s >> 5, cid = s & 31;
      short8 v = *(const short8*)&o_scr[obase + tl * 256 + cid * 8];
      *(short8*)&sx[tl * 256 + ((cid ^ (tl & 7)) << 3)] = v;
    }
    __syncthreads();

    floatx4 fa[8][2] = {};   // [nt = token tile][mt = co tile]
#pragma unroll
    for (int kc = 0; kc < 8; ++kc) {
      short8 Atok[8], Bw[2];
#pragma unroll
      for (int nt = 0; nt < 8; ++nt) Atok[nt] = ldsfrag(nt * 16 + l15, kc);
#pragma unroll
      for (int mt = 0; mt < 2; ++mt)
        Bw[mt] = wpfrag(wbf, 48 + wv * 2 + mt, kc, lane);
#pragma unroll
      for (int nt = 0; nt < 8; ++nt)
#pragma unroll
        for (int mt = 0; mt < 2; ++mt)
          fa[nt][mt] = __builtin_amdgcn_mfma_f32_16x16x32_bf16(Atok[nt], Bw[mt], fa[nt][mt], 0, 0, 0);
    }

    // epilogue: lane holds 4 consecutive w (row = 4g+r) for one co (col = l15)
#pragma unroll
    for (int nt = 0; nt < 8; ++nt)
#pragma unroll
      for (int mt = 0; mt < 2; ++mt) {
        int co = wv * 32 + mt * 16 + l15;
        size_t addr = (((size_t)(b * 256 + co)) << 16) + (size_t)h * 256 +
                      hf * 128 + nt * 16 + 4 * g;
        floatx4 xv = *(const floatx4*)(x + addr);
        floatx4 o;
#pragma unroll
        for (int r = 0; r < 4; ++r) o[r] = fa[nt][mt][r] + xv[r];
        *(floatx4*)(out + addr) = o;
      }
    __syncthreads();
  }
}

// ================= fallback (fused r13-form) if d_ws too small =============
__global__ __launch_bounds__(512, 2) void fused_fallback(
    const float* __restrict__ x, const float* __restrict__ gamma,
    const float* __restrict__ beta, const unsigned short* __restrict__ wbf,
    float* __restrict__ out) {
  __shared__ __align__(16) unsigned short sres[256 * 128];
  __shared__ __align__(16) unsigned short sxn[128 * 256];

  const int tid = threadIdx.x;
  const int lane = tid & 63;
  const int wv = tid >> 6;
  const int g = lane >> 4;
  const int l15 = lane & 15;

  const int id = ((blockIdx.x & 7) << 8) + (blockIdx.x >> 3);
  const int b = id >> 9;
  const int wy = (id >> 4) & 31;
  const int wxp = id & 15;
  const size_t xbase = ((size_t)b << 24) + (size_t)(wy * 8) * 256 + (size_t)(wxp * 16);

#pragma unroll
  for (int it = 0; it < 16; ++it) {
    int s = it * 512 + tid;
    int c = s >> 5, i = (s >> 2) & 7, j4 = s & 3;
    floatx4 v = *(const floatx4*)(x + xbase + (size_t)c * 65536 + i * 256 + j4 * 4);
    ushort4v u;
    u.x = f2bf(v.x); u.y = f2bf(v.y); u.z = f2bf(v.z); u.w = f2bf(v.w);
    *(ushort4v*)&sres[ridx2(c, i * 16 + j4 * 4)] = u;
  }
  __syncthreads();

  const int t = tid & 127;
  const int q = tid >> 7;
  float s1 = 0.f, s2 = 0.f;
#pragma unroll 8
  for (int cc = 0; cc < 64; ++cc) {
    float xv = bf2f(sres[ridx2(q * 64 + cc, t)]);
    s1 += xv; s2 += xv * xv;
  }
  { floatx2 p; p.x = s1; p.y = s2; ((floatx2*)sxn)[q * 128 + t] = p; }
  __syncthreads();

  float S1 = 0.f, S2 = 0.f;
#pragma unroll
  for (int p = 0; p < 4; ++p) {
    floatx2 pp = ((const floatx2*)sxn)[p * 128 + t];
    S1 += pp.x; S2 += pp.y;
  }
  const float mu = S1 * (1.f / 256.f);
  const float rstd = rsqrtf(S2 * (1.f / 256.f) - mu * mu + 1e-5f);
  __syncthreads();

#pragma unroll
  for (int kk = 0; kk < 2; ++kk) {
    int kc = q * 2 + kk;
#pragma unroll
    for (int gc = 0; gc < 4; ++gc) {
      short8 s8;
#pragma unroll
      for (int hf = 0; hf < 2; ++hf)
#pragma unroll
        for (int e = 0; e < 4; ++e) {
          int c = kc * 32 + hf * 16 + gc * 4 + e;
          float xv = bf2f(sres[ridx2(c, t)]);
          float val = (xv - mu) * rstd * gamma[c] + beta[c];
          s8[hf * 4 + e] = (short)f2bf(val);
        }
      *(short8*)&sxn[xnaddr(t, kc * 4 + gc)] = s8;
    }
  }
  __syncthreads();

  auto ldsfrag = [&](int row, int kc) -> short8 {
    return *(const short8*)&sxn[xnaddr(row, kc * 4 + g)];
  };

  const int head = wv >> 1;
  const int win = wv & 1;
  auto srow = [&](int tl) { return (((tl) >> 3) << 4) + win * 8 + ((tl) & 7); };

  short8 qkf[2][4][2];
#pragma unroll
  for (int qk = 0; qk < 2; ++qk) {
    floatx4 acc[4][4] = {};
    const int rbq = qk * 16 + head * 4;
#pragma unroll
    for (int kc = 0; kc < 8; ++kc) {
      short8 Bv[4], Av[4];
#pragma unroll
      for (int nt = 0; nt < 4; ++nt) Bv[nt] = ldsfrag(srow(nt * 16 + l15), kc);
#pragma unroll
      for (int mt = 0; mt < 4; ++mt)
        Av[mt] = wpfrag(wbf, rbq + mt, kc, lane);
#pragma unroll
      for (int mt = 0; mt < 4; ++mt)
#pragma unroll
        for (int nt = 0; nt < 4; ++nt)
          acc[mt][nt] = __builtin_amdgcn_mfma_f32_16x16x32_bf16(Av[mt], Bv[nt], acc[mt][nt], 0, 0, 0);
    }
#pragma unroll
    for (int nt = 0; nt < 4; ++nt)
#pragma unroll
      for (int ks = 0; ks < 2; ++ks) {
        short8 f;
#pragma unroll
        for (int e = 0; e < 4; ++e) {
          f[e]     = (short)f2bf(acc[2 * ks][nt][e]);
          f[4 + e] = (short)f2bf(acc[2 * ks + 1][nt][e]);
        }
        qkf[qk][nt][ks] = f;
      }
  }

  floatx4 sa[4][4] = {};
#pragma unroll
  for (int ks = 0; ks < 2; ++ks)
#pragma unroll
    for (int mts = 0; mts < 4; ++mts)
#pragma unroll
      for (int nts = 0; nts < 4; ++nts)
        sa[mts][nts] = __builtin_amdgcn_mfma_f32_16x16x32_bf16(qkf[1][mts][ks], qkf[0][nts][ks], sa[mts][nts], 0, 0, 0);

  short8 pf[4][2];
  const float CEXP = 0.125f * 1.44269504088896f;
#pragma unroll
  for (int nts = 0; nts < 4; ++nts) {
    float m = sa[0][nts][0];
#pragma unroll
    for (int mts = 0; mts < 4; ++mts)
#pragma unroll
      for (int r = 0; r < 4; ++r) m = fmaxf(m, sa[mts][nts][r]);
    m = fmaxf(m, __shfl_xor(m, 16));
    m = fmaxf(m, __shfl_xor(m, 32));
    float sum = 0.f;
#pragma unroll
    for (int mts = 0; mts < 4; ++mts)
#pragma unroll
      for (int r = 0; r < 4; ++r) {
        float p = __builtin_amdgcn_exp2f((sa[mts][nts][r] - m) * CEXP);
        sa[mts][nts][r] = p;
        sum += p;
      }
    sum += __shfl_xor(sum, 16);
    sum += __shfl_xor(sum, 32);
    float inv = __builtin_amdgcn_rcpf(sum);
#pragma unroll
    for (int ks = 0; ks < 2; ++ks) {
      short8 f;
#pragma unroll
      for (int e = 0; e < 4; ++e) {
        f[e]     = (short)f2bf(sa[2 * ks][nts][e] * inv);
        f[4 + e] = (short)f2bf(sa[2 * ks + 1][nts][e] * inv);
      }
      pf[nts][ks] = f;
    }
  }

  short8 vf[4][2];
  {
    floatx4 acc[4][4] = {};
#pragma unroll
    for (int kc = 0; kc < 8; ++kc) {
      short8 Av[4], Bv[4];
#pragma unroll
      for (int mt = 0; mt < 4; ++mt) Av[mt] = ldsfrag(srow(mt * 16 + l15), kc);
#pragma unroll
      for (int nt = 0; nt < 4; ++nt)
        Bv[nt] = wpfrag(wbf, 32 + head * 4 + nt, kc, lane);
#pragma unroll
      for (int mt = 0; mt < 4; ++mt)
#pragma unroll
        for (int nt = 0; nt < 4; ++nt)
          acc[mt][nt] = __builtin_amdgcn_mfma_f32_16x16x32_bf16(Av[mt], Bv[nt], acc[mt][nt], 0, 0, 0);
    }
#pragma unroll
    for (int nt = 0; nt < 4; ++nt)
#pragma unroll
      for (int ks = 0; ks < 2; ++ks) {
        short8 f;
#pragma unroll
        for (int e = 0; e < 4; ++e) {
          f[e]     = (short)f2bf(acc[2 * ks][nt][e]);
          f[4 + e] = (short)f2bf(acc[2 * ks + 1][nt][e]);
        }
        vf[nt][ks] = f;
      }
  }

  floatx4 oa[4][4] = {};
#pragma unroll
  for (int ks = 0; ks < 2; ++ks)
#pragma unroll
    for (int ntq = 0; ntq < 4; ++ntq)
#pragma unroll
      for (int dt = 0; dt < 4; ++dt)
        oa[ntq][dt] = __builtin_amdgcn_mfma_f32_16x16x32_bf16(pf[ntq][ks], vf[dt][ks], oa[ntq][dt], 0, 0, 0);

  __syncthreads();

#pragma unroll
  for (int ntq = 0; ntq < 4; ++ntq)
#pragma unroll
    for (int dt = 0; dt < 4; ++dt) {
      int c = head * 64 + dt * 16 + l15;
      int kc = c >> 5, hf = (c >> 4) & 1, gc = (c >> 2) & 3, e = c & 3;
#pragma unroll
      for (int r = 0; r < 4; ++r) {
        int tq = ntq * 16 + 4 * g + r;
        int sr = srow(tq);
        sxn[sr * 256 + (((kc * 4 + gc) ^ (sr & 7)) << 3) + hf * 4 + e] =
            f2bf(oa[ntq][dt][r]);
      }
    }
  __syncthreads();

  floatx4 fa[2][8] = {};
#pragma unroll
  for (int kc = 0; kc < 8; ++kc) {
    short8 Bv[8], Av[2];
#pragma unroll
    for (int nt = 0; nt < 8; ++nt) Bv[nt] = ldsfrag(nt * 16 + l15, kc);
#pragma unroll
    for (int mt = 0; mt < 2; ++mt)
      Av[mt] = wpfrag(wbf, 48 + wv * 2 + mt, kc, lane);
#pragma unroll
    for (int mt = 0; mt < 2; ++mt)
#pragma unroll
      for (int nt = 0; nt < 8; ++nt)
        fa[mt][nt] = __builtin_amdgcn_mfma_f32_16x16x32_bf16(Av[mt], Bv[nt], fa[mt][nt], 0, 0, 0);
  }

#pragma unroll
  for (int mt = 0; mt < 2; ++mt)
#pragma unroll
    for (int nt = 0; nt < 8; ++nt)
#pragma unroll
      for (int r = 0; r < 4; ++r) {
        int co = wv * 32 + mt * 16 + 4 * g + r;
        int tt = nt * 16 + l15;
        float val = fa[mt][nt][r] + bf2f(sres[ridx2(co, tt)]);
        out[((size_t)(b * 256 + co) << 16) + (size_t)(wy * 8 + (tt >> 4)) * 256 +
            (wxp * 16 + (tt & 15))] = val;
      }
}

extern "C" void kernel_launch(void* const* d_in, const int* in_sizes, int n_in,
                              void* d_out, int out_size, void* d_ws, size_t ws_size,
                              hipStream_t stream) {
  const float* x     = (const float*)d_in[0];
  const float* gamma = (const float*)d_in[1];
  const float* beta  = (const float*)d_in[2];
  const float* wqkv  = (const float*)d_in[3];
  const float* wout  = (const float*)d_in[4];
  float* out = (float*)d_out;

  unsigned short* wbf   = (unsigned short*)d_ws;             // 512 KB packed bf16 weights
  unsigned short* o_scr = wbf + 262144;                      // 128 MB o scratch

  const size_t need = 512 * 1024 + (size_t)128 * 1024 * 1024;

  wconv<<<128, 256, 0, stream>>>(wqkv, wout, wbf);
  if (ws_size >= need) {
    k1_fused<<<2048, 512, 0, stream>>>(x, gamma, beta, wbf, o_scr);
    k2_proj<<<1024, 512, 0, stream>>>(o_scr, x, wbf, out);
  } else {
    fused_fallback<<<2048, 512, 0, stream>>>(x, gamma, beta, wbf, out);
  }
}